// Round 1
// baseline (1326.015 us; speedup 1.0000x reference)
//
#include <hip/hip_runtime.h>
#include <math.h>

#define B_ 64
#define C_ 8
#define T_ 2048
#define K_ 64
#define NF_ 32
#define FFT_DIM_ 512
#define MLP_ 32
#define HID_ 64
#define W_ 1985
#define CH_ 32
#define NCHUNK_ 63   /* ceil(1985/32) */
#define PI_F 3.14159265358979323846f

// ---------------------------------------------------------------------------
// K1: softmax stats over agg (W,) -> ws[0]=max, ws[1]=sum(exp(agg-max))
// ---------------------------------------------------------------------------
__global__ __launch_bounds__(256) void k_softmax_stats(
    const float* __restrict__ agg, float* __restrict__ ws)
{
    __shared__ float red[256];
    const int t = threadIdx.x;
    float m = -1e30f;
    for (int i = t; i < W_; i += 256) m = fmaxf(m, agg[i]);
    red[t] = m;
    __syncthreads();
    for (int s = 128; s > 0; s >>= 1) {
        if (t < s) red[t] = fmaxf(red[t], red[t + s]);
        __syncthreads();
    }
    const float mx = red[0];
    __syncthreads();
    float sum = 0.f;
    for (int i = t; i < W_; i += 256) sum += expf(agg[i] - mx);
    red[t] = sum;
    __syncthreads();
    for (int s = 128; s > 0; s >>= 1) {
        if (t < s) red[t] += red[t + s];
        __syncthreads();
    }
    if (t == 0) { ws[0] = mx; ws[1] = red[0]; }
}

// ---------------------------------------------------------------------------
// K2: fused sliding-DFT features + MLP + weighted partial sum per (b, chunk)
// ---------------------------------------------------------------------------
__global__ __launch_bounds__(256) void k_main(
    const float* __restrict__ x,  const float* __restrict__ pw,
    const float* __restrict__ pb, const float* __restrict__ w0g,
    const float* __restrict__ b0g,const float* __restrict__ a0g,
    const float* __restrict__ w1g,const float* __restrict__ b1g,
    const float* __restrict__ a1g,const float* __restrict__ wog,
    const float* __restrict__ bog,const float* __restrict__ agg,
    const float* __restrict__ stats, float* __restrict__ partial)
{
    __shared__ float twc[64], tws[64];
    __shared__ __align__(16) float xtile[C_][CH_ + 64];   // 8 x 96
    __shared__ __align__(16) float featL[16][516];        // batch of 16 w, pad 516
    __shared__ __align__(16) float projL[16][36];
    __shared__ __align__(16) float h0L[16][68];
    __shared__ __align__(16) float h1L[16][36];
    __shared__ float chunkAcc[CH_];

    const int t     = threadIdx.x;
    const int chunk = blockIdx.x;
    const int b     = blockIdx.y;
    const int w0c   = chunk * CH_;

    // ---- stage twiddles + x tile ----
    if (t < 64) {
        float s, c;
        sincosf(6.28318530717958647692f * (float)t / 64.0f, &s, &c);
        twc[t] = c; tws[t] = s;
    }
    for (int i = t; i < C_ * (CH_ + 64); i += 256) {
        const int c = i / (CH_ + 64);
        const int j = i - c * (CH_ + 64);
        int gi = w0c + j; if (gi > T_ - 1) gi = T_ - 1;
        xtile[c][j] = x[((size_t)b * C_ + c) * T_ + gi];
    }
    __syncthreads();

    // ---- seed DFT for this thread's (c,f) chain at w = w0c ----
    const int cc = t >> 5;      // 0..7
    const int ff = t & 31;      // 0..31
    float re = 0.f, im = 0.f;
    {
        int m = 0;
        #pragma unroll 8
        for (int k = 0; k < 64; ++k) {
            const float xv = xtile[cc][k];
            re += xv * twc[m];
            im -= xv * tws[m];
            m = (m + ff) & 63;
        }
    }
    const float cf = twc[ff];   // rotation e^{+2*pi*i*f/64}
    const float sf = tws[ff];

    // ---- MLP-phase thread mapping ----
    const int lane = t & 63;
    const int v    = t >> 6;     // wave 0..3
    const int wm   = lane >> 2;  // 0..15 : w within batch
    const int oi   = lane & 3;

    const float mx   = stats[0];
    const float rden = 1.0f / stats[1];

    for (int batch = 0; batch < 2; ++batch) {
        // ===== phase A: emit features for 16 w, slide chain =====
        #pragma unroll 4
        for (int wl = 0; wl < 16; ++wl) {
            const int wrel = batch * 16 + wl;
            const float mag = log1pf(sqrtf(re * re + im * im));
            const float ph  = atan2f(im, re) * (1.0f / PI_F);
            float2* dst = (float2*)&featL[wl][cc * 64 + 2 * ff];
            *dst = make_float2(mag, ph);
            // slide w -> w+1
            const float d  = xtile[cc][wrel + 64] - xtile[cc][wrel];
            const float tt = re + d;
            re = tt * cf - im * sf;
            im = tt * sf + im * cf;
        }
        __syncthreads();

        // ===== phase B1: proj = tanh(feat @ pw^T + pb) * pi =====
        {
            const int o1 = v * 8 + oi;
            const int o2 = o1 + 4;
            const float4* fr = (const float4*)&featL[wm][0];
            const float4* p1 = (const float4*)&pw[(size_t)o1 * FFT_DIM_];
            const float4* p2 = (const float4*)&pw[(size_t)o2 * FFT_DIM_];
            float acc1a = 0.f, acc1b = 0.f, acc2a = 0.f, acc2b = 0.f;
            #pragma unroll 8
            for (int jg = 0; jg < 128; jg += 2) {
                const float4 fA = fr[jg],   fB = fr[jg + 1];
                const float4 qA = p1[jg],   qB = p1[jg + 1];
                const float4 rA = p2[jg],   rB = p2[jg + 1];
                acc1a += fA.x * qA.x + fA.y * qA.y + fA.z * qA.z + fA.w * qA.w;
                acc1b += fB.x * qB.x + fB.y * qB.y + fB.z * qB.z + fB.w * qB.w;
                acc2a += fA.x * rA.x + fA.y * rA.y + fA.z * rA.z + fA.w * rA.w;
                acc2b += fB.x * rB.x + fB.y * rB.y + fB.z * rB.z + fB.w * rB.w;
            }
            const float pr1 = tanhf(acc1a + acc1b + pb[o1]) * PI_F;
            const float pr2 = tanhf(acc2a + acc2b + pb[o2]) * PI_F;
            projL[wm][o1] = pr1;
            projL[wm][o2] = pr2;
        }
        __syncthreads();

        // ===== phase B2: h0 = snake(proj @ w0^T + b0, a0) (64 outputs) =====
        {
            const float4* prr = (const float4*)&projL[wm][0];
            float4 q[8];
            #pragma unroll
            for (int ig = 0; ig < 8; ++ig) q[ig] = prr[ig];
            #pragma unroll
            for (int j = 0; j < 4; ++j) {
                const int o = v * 16 + oi + 4 * j;
                const float4* wr = (const float4*)&w0g[(size_t)o * MLP_];
                float acc = 0.f;
                #pragma unroll
                for (int ig = 0; ig < 8; ++ig) {
                    const float4 wv = wr[ig];
                    acc += q[ig].x * wv.x + q[ig].y * wv.y + q[ig].z * wv.z + q[ig].w * wv.w;
                }
                const float hv = acc + b0g[o];
                const float aa = fabsf(a0g[o]) + 1e-8f;
                const float sn = sinf(aa * hv);
                h0L[wm][o] = hv + sn * sn / aa;
            }
        }
        __syncthreads();

        // ===== phase B3: h1 = snake(h0 @ w1^T + b1, a1) (32 outputs) =====
        {
            const int o1 = v * 8 + oi;
            const int o2 = o1 + 4;
            const float4* hr = (const float4*)&h0L[wm][0];
            const float4* wa = (const float4*)&w1g[(size_t)o1 * HID_];
            const float4* wb = (const float4*)&w1g[(size_t)o2 * HID_];
            float acc1 = 0.f, acc2 = 0.f;
            #pragma unroll
            for (int jg = 0; jg < 16; ++jg) {
                const float4 hv = hr[jg];
                const float4 va = wa[jg];
                const float4 vb = wb[jg];
                acc1 += hv.x * va.x + hv.y * va.y + hv.z * va.z + hv.w * va.w;
                acc2 += hv.x * vb.x + hv.y * vb.y + hv.z * vb.z + hv.w * vb.w;
            }
            float hv1 = acc1 + b1g[o1];
            float aa1 = fabsf(a1g[o1]) + 1e-8f;
            float s1  = sinf(aa1 * hv1);
            h1L[wm][o1] = hv1 + s1 * s1 / aa1;
            float hv2 = acc2 + b1g[o2];
            float aa2 = fabsf(a1g[o2]) + 1e-8f;
            float s2  = sinf(aa2 * hv2);
            h1L[wm][o2] = hv2 + s2 * s2 / aa2;
        }
        __syncthreads();

        // ===== phase B4: out_t = h1 @ wo^T + bo; apply softmax weight =====
        if (t < 16) {
            const int w = t;
            const float4* hr = (const float4*)&h1L[w][0];
            const float4* wr = (const float4*)&wog[0];
            float acc = 0.f;
            #pragma unroll
            for (int jg = 0; jg < 8; ++jg) {
                const float4 hv = hr[jg];
                const float4 wv = wr[jg];
                acc += hv.x * wv.x + hv.y * wv.y + hv.z * wv.z + hv.w * wv.w;
            }
            const float val = acc + bog[0];
            const int wg = w0c + batch * 16 + w;
            const float sw = (wg < W_) ? expf(agg[wg] - mx) * rden : 0.f;
            chunkAcc[batch * 16 + w] = val * sw;
        }
        __syncthreads();
    }

    // ---- reduce 32 chunk values -> 1 partial ----
    if (t < 32) {
        float vs = chunkAcc[t];
        vs += __shfl_down(vs, 16);
        vs += __shfl_down(vs, 8);
        vs += __shfl_down(vs, 4);
        vs += __shfl_down(vs, 2);
        vs += __shfl_down(vs, 1);
        if (t == 0) partial[(size_t)chunk * B_ + b] = vs;
    }
}

// ---------------------------------------------------------------------------
// K3: final reduce over chunks -> d_out[b]
// ---------------------------------------------------------------------------
__global__ void k_reduce(const float* __restrict__ partial, float* __restrict__ out)
{
    const int b = threadIdx.x;
    if (b < B_) {
        float s = 0.f;
        for (int c = 0; c < NCHUNK_; ++c) s += partial[(size_t)c * B_ + b];
        out[b] = s;
    }
}

// ---------------------------------------------------------------------------
extern "C" void kernel_launch(void* const* d_in, const int* in_sizes, int n_in,
                              void* d_out, int out_size, void* d_ws, size_t ws_size,
                              hipStream_t stream)
{
    const float* x   = (const float*)d_in[0];
    const float* pw  = (const float*)d_in[1];
    const float* pb  = (const float*)d_in[2];
    const float* w0  = (const float*)d_in[3];
    const float* b0  = (const float*)d_in[4];
    const float* a0  = (const float*)d_in[5];
    const float* w1  = (const float*)d_in[6];
    const float* b1  = (const float*)d_in[7];
    const float* a1  = (const float*)d_in[8];
    const float* wo  = (const float*)d_in[9];
    const float* bo  = (const float*)d_in[10];
    const float* agg = (const float*)d_in[11];
    float* ws  = (float*)d_ws;
    float* out = (float*)d_out;

    k_softmax_stats<<<1, 256, 0, stream>>>(agg, ws);
    dim3 grid(NCHUNK_, B_);
    k_main<<<grid, 256, 0, stream>>>(x, pw, pb, w0, b0, a0, w1, b1, a1, wo, bo,
                                     agg, ws, ws + 2);
    k_reduce<<<1, 64, 0, stream>>>(ws + 2, out);
}

// Round 2
// 506.729 us; speedup vs baseline: 2.6168x; 2.6168x over previous
//
#include <hip/hip_runtime.h>
#include <math.h>

#define B_ 64
#define C_ 8
#define T_ 2048
#define K_ 64
#define NF_ 32
#define FFT_DIM_ 512
#define MLP_ 32
#define HID_ 64
#define W_ 1985
#define CH_ 32
#define NCHUNK_ 63   /* ceil(1985/32) */
#define PI_F 3.14159265358979323846f

// ---------------------------------------------------------------------------
// K1: softmax stats over agg (W,) -> ws[0]=max, ws[1]=sum(exp(agg-max))
// ---------------------------------------------------------------------------
__global__ __launch_bounds__(256) void k_softmax_stats(
    const float* __restrict__ agg, float* __restrict__ ws)
{
    __shared__ float red[256];
    const int t = threadIdx.x;
    float m = -1e30f;
    for (int i = t; i < W_; i += 256) m = fmaxf(m, agg[i]);
    red[t] = m;
    __syncthreads();
    for (int s = 128; s > 0; s >>= 1) {
        if (t < s) red[t] = fmaxf(red[t], red[t + s]);
        __syncthreads();
    }
    const float mx = red[0];
    __syncthreads();
    float sum = 0.f;
    for (int i = t; i < W_; i += 256) sum += expf(agg[i] - mx);
    red[t] = sum;
    __syncthreads();
    for (int s = 128; s > 0; s >>= 1) {
        if (t < s) red[t] += red[t + s];
        __syncthreads();
    }
    if (t == 0) { ws[0] = mx; ws[1] = red[0]; }
}

// ---------------------------------------------------------------------------
// K2: fused sliding-DFT features + reg-tiled proj GEMM + MLP per (b, chunk)
// ---------------------------------------------------------------------------
__global__ __launch_bounds__(256) void k_main(
    const float* __restrict__ x,  const float* __restrict__ pw,
    const float* __restrict__ pb, const float* __restrict__ w0g,
    const float* __restrict__ b0g,const float* __restrict__ a0g,
    const float* __restrict__ w1g,const float* __restrict__ b1g,
    const float* __restrict__ a1g,const float* __restrict__ wog,
    const float* __restrict__ bog,const float* __restrict__ agg,
    const float* __restrict__ stats, float* __restrict__ partial)
{
    // featL: 32 w-rows x 516 floats (rows 16B-aligned; 516%32=4 -> benign
    // 2-way max aliasing). Dead after the GEMM -> overlaid by pacc/h0/h1.
    __shared__ __align__(16) float featL[CH_ * 516];      // 66048 B
    __shared__ __align__(16) float projL[CH_ * 36];       // 4608 B
    __shared__ __align__(16) float xtile[C_][100];        // 3200 B
    __shared__ float twc[64], tws[64];
    __shared__ float chunkAcc[CH_];

    float* pacc = featL;                          // [2][32][33] = 8448 B
    float* h0L  = featL;                          // [32][68]    = 8704 B (after pacc dead)
    float* h1L  = featL + 16384;                  // [32][36]    = 4608 B

    const int t     = threadIdx.x;
    const int chunk = blockIdx.x;
    const int b     = blockIdx.y;
    const int w0c   = chunk * CH_;

    // ---- stage twiddles + x tile ----
    if (t < 64) {
        float s, c;
        sincosf(6.28318530717958647692f * (float)t / 64.0f, &s, &c);
        twc[t] = c; tws[t] = s;
    }
    for (int i = t; i < C_ * 96; i += 256) {
        const int c = i / 96;
        const int j = i - c * 96;
        int gi = w0c + j; if (gi > T_ - 1) gi = T_ - 1;
        xtile[c][j] = x[((size_t)b * C_ + c) * T_ + gi];
    }
    __syncthreads();

    // ---- seed DFT for this thread's (c,f) chain at w = w0c ----
    const int cc = t >> 5;      // 0..7
    const int ff = t & 31;      // 0..31
    float re = 0.f, im = 0.f;
    {
        int m = 0;
        #pragma unroll 8
        for (int k = 0; k < 64; ++k) {
            const float xv = xtile[cc][k];
            re += xv * twc[m];
            im -= xv * tws[m];
            m = (m + ff) & 63;
        }
    }
    const float cf = twc[ff];   // rotation e^{+2*pi*i*f/64}
    const float sf = tws[ff];

    // ---- phase A: emit features for all 32 w, sliding the chain ----
    #pragma unroll 4
    for (int wl = 0; wl < CH_; ++wl) {
        const float mag = log1pf(sqrtf(re * re + im * im));
        const float ph  = atan2f(im, re) * (1.0f / PI_F);
        *(float2*)&featL[wl * 516 + cc * 64 + 2 * ff] = make_float2(mag, ph);
        const float d  = xtile[cc][wl + 64] - xtile[cc][wl];
        const float tt = re + d;
        re = tt * cf - im * sf;
        im = tt * sf + im * cf;
    }
    __syncthreads();

    // ---- phase B: proj GEMM, 32w x 32o, K=512, K-split 2 ----
    // thread: ks = K-half, wg -> 4 w rows, og -> o and o+16. 8 acc/thread.
    {
        const int ks = t >> 7;          // 0..1
        const int r  = t & 127;
        const int wb = (r >> 4) * 4;    // 0,4,...,28
        const int og = r & 15;
        const int o0 = og, o1 = og + 16;
        const int kb4 = ks * 64;        // float4 offset into K

        const float4* pw4 = (const float4*)pw;
        float acc[4][2];
        #pragma unroll
        for (int i = 0; i < 4; ++i) { acc[i][0] = 0.f; acc[i][1] = 0.f; }

        #pragma unroll 4
        for (int jg = 0; jg < 64; ++jg) {
            float4 p0 = pw4[(size_t)o0 * 128 + kb4 + jg];
            float4 p1 = pw4[(size_t)o1 * 128 + kb4 + jg];
            #pragma unroll
            for (int i = 0; i < 4; ++i) {
                const float4 f = *(const float4*)&featL[(wb + i) * 516 + (kb4 + jg) * 4];
                acc[i][0] += f.x * p0.x + f.y * p0.y + f.z * p0.z + f.w * p0.w;
                acc[i][1] += f.x * p1.x + f.y * p1.y + f.z * p1.z + f.w * p1.w;
            }
        }
        __syncthreads();   // featL reads done; safe to overlay with pacc
        #pragma unroll
        for (int i = 0; i < 4; ++i) {
            pacc[(ks * CH_ + wb + i) * 33 + o0] = acc[i][0];
            pacc[(ks * CH_ + wb + i) * 33 + o1] = acc[i][1];
        }
    }
    __syncthreads();

    // ---- finalize proj: reduce K-halves, bias, tanh ----
    {
        const int o  = t & 31;
        const int wq = (t >> 5) * 4;
        const float pbv = pb[o];
        #pragma unroll
        for (int i = 0; i < 4; ++i) {
            const int w = wq + i;
            const float s = pacc[w * 33 + o] + pacc[(CH_ + w) * 33 + o] + pbv;
            projL[w * 36 + o] = tanhf(s) * PI_F;
        }
    }
    __syncthreads();

    // ---- h0 = snake(proj @ w0^T + b0): thread = (w, 8 outputs) ----
    {
        const int w  = t >> 3;
        const int ob = (t & 7) * 8;
        float4 pr[8];
        #pragma unroll
        for (int q = 0; q < 8; ++q) pr[q] = *(const float4*)&projL[w * 36 + q * 4];
        #pragma unroll
        for (int k = 0; k < 8; ++k) {
            const int o = ob + k;
            const float4* wr = (const float4*)&w0g[(size_t)o * MLP_];
            float acc = 0.f;
            #pragma unroll
            for (int q = 0; q < 8; ++q) {
                const float4 wv = wr[q];
                acc += pr[q].x * wv.x + pr[q].y * wv.y + pr[q].z * wv.z + pr[q].w * wv.w;
            }
            const float hv = acc + b0g[o];
            const float aa = fabsf(a0g[o]) + 1e-8f;
            const float sn = sinf(aa * hv);
            h0L[w * 68 + o] = hv + sn * sn / aa;   // overlays pacc (dead)
        }
    }
    __syncthreads();

    // ---- h1 = snake(h0 @ w1^T + b1): thread = (w, 4 outputs) ----
    {
        const int w  = t >> 3;
        const int o4 = (t & 7) * 4;
        float4 hr[16];
        #pragma unroll
        for (int q = 0; q < 16; ++q) hr[q] = *(const float4*)&h0L[w * 68 + q * 4];
        #pragma unroll
        for (int k = 0; k < 4; ++k) {
            const int o = o4 + k;
            const float4* wr = (const float4*)&w1g[(size_t)o * HID_];
            float acc = 0.f;
            #pragma unroll
            for (int q = 0; q < 16; ++q) {
                const float4 wv = wr[q];
                acc += hr[q].x * wv.x + hr[q].y * wv.y + hr[q].z * wv.z + hr[q].w * wv.w;
            }
            const float hv = acc + b1g[o];
            const float aa = fabsf(a1g[o]) + 1e-8f;
            const float sn = sinf(aa * hv);
            h1L[w * 36 + o] = hv + sn * sn / aa;
        }
    }
    __syncthreads();

    // ---- out_t + softmax weight ----
    if (t < CH_) {
        const int w = t;
        const float4* hr = (const float4*)&h1L[w * 36];
        const float4* wr = (const float4*)&wog[0];
        float acc = 0.f;
        #pragma unroll
        for (int q = 0; q < 8; ++q) {
            const float4 hv = hr[q];
            const float4 wv = wr[q];
            acc += hv.x * wv.x + hv.y * wv.y + hv.z * wv.z + hv.w * wv.w;
        }
        const float val = acc + bog[0];
        const int wg = w0c + w;
        const float sw = (wg < W_) ? expf(agg[wg] - stats[0]) / stats[1] : 0.f;
        chunkAcc[w] = val * sw;
    }
    __syncthreads();

    // ---- reduce 32 chunk values -> 1 partial ----
    if (t < 32) {
        float vs = chunkAcc[t];
        vs += __shfl_down(vs, 16);
        vs += __shfl_down(vs, 8);
        vs += __shfl_down(vs, 4);
        vs += __shfl_down(vs, 2);
        vs += __shfl_down(vs, 1);
        if (t == 0) partial[(size_t)chunk * B_ + b] = vs;
    }
}

// ---------------------------------------------------------------------------
// K3: final reduce over chunks -> d_out[b]
// ---------------------------------------------------------------------------
__global__ void k_reduce(const float* __restrict__ partial, float* __restrict__ out)
{
    const int b = threadIdx.x;
    if (b < B_) {
        float s = 0.f;
        for (int c = 0; c < NCHUNK_; ++c) s += partial[(size_t)c * B_ + b];
        out[b] = s;
    }
}

// ---------------------------------------------------------------------------
extern "C" void kernel_launch(void* const* d_in, const int* in_sizes, int n_in,
                              void* d_out, int out_size, void* d_ws, size_t ws_size,
                              hipStream_t stream)
{
    const float* x   = (const float*)d_in[0];
    const float* pw  = (const float*)d_in[1];
    const float* pb  = (const float*)d_in[2];
    const float* w0  = (const float*)d_in[3];
    const float* b0  = (const float*)d_in[4];
    const float* a0  = (const float*)d_in[5];
    const float* w1  = (const float*)d_in[6];
    const float* b1  = (const float*)d_in[7];
    const float* a1  = (const float*)d_in[8];
    const float* wo  = (const float*)d_in[9];
    const float* bo  = (const float*)d_in[10];
    const float* agg = (const float*)d_in[11];
    float* ws  = (float*)d_ws;
    float* out = (float*)d_out;

    k_softmax_stats<<<1, 256, 0, stream>>>(agg, ws);
    dim3 grid(NCHUNK_, B_);
    k_main<<<grid, 256, 0, stream>>>(x, pw, pb, w0, b0, a0, w1, b1, a1, wo, bo,
                                     agg, ws, ws + 2);
    k_reduce<<<1, 64, 0, stream>>>(ws + 2, out);
}

// Round 3
// 483.865 us; speedup vs baseline: 2.7405x; 1.0473x over previous
//
#include <hip/hip_runtime.h>
#include <math.h>

#define B_ 64
#define C_ 8
#define T_ 2048
#define K_ 64
#define NF_ 32
#define FFT_DIM_ 512
#define MLP_ 32
#define HID_ 64
#define W_ 1985
#define CH_ 32
#define NCHUNK_ 63   /* ceil(1985/32) */
#define PI_F 3.14159265358979323846f

// ---------------- fast inline transcendentals (branchless) ----------------
__device__ __forceinline__ float fast_rcp(float x) { return __builtin_amdgcn_rcpf(x); }

// atan2(y,x)/pi, max err ~1e-6. Handles quadrants; x=y=0 guarded.
__device__ __forceinline__ float fast_atan2pi(float y, float x)
{
    const float ax = fabsf(x), ay = fabsf(y);
    const float mx = fmaxf(ax, ay), mn = fminf(ax, ay);
    const float r  = mn * fast_rcp(fmaxf(mx, 1e-30f));
    const float t  = r * r;
    // atan(r)/pi on [0,1], degree-11 odd minimax
    float a = -0.003730950f;
    a = fmaf(a, t,  0.016759940f);
    a = fmaf(a, t, -0.037059946f);
    a = fmaf(a, t,  0.061602941f);
    a = fmaf(a, t, -0.105877528f);
    a = fmaf(a, t,  0.318302656f);
    a *= r;
    a = (ay > ax) ? (0.5f - a) : a;
    a = (x < 0.0f) ? (1.0f - a) : a;
    return copysignf(a, y);
}

__device__ __forceinline__ float fast_tanh(float x)
{
    const float e = __expf(2.0f * x);
    return 1.0f - 2.0f * fast_rcp(e + 1.0f);
}

__device__ __forceinline__ float fast_snake(float h, float rcp_aa, float aa)
{
    const float s = __sinf(aa * h);
    return h + s * s * rcp_aa;
}

// ---------------------------------------------------------------------------
// K1: softmax stats over agg (W,) -> ws[0]=max, ws[1]=sum(exp(agg-max))
// ---------------------------------------------------------------------------
__global__ __launch_bounds__(256) void k_softmax_stats(
    const float* __restrict__ agg, float* __restrict__ ws)
{
    __shared__ float red[256];
    const int t = threadIdx.x;
    float m = -1e30f;
    for (int i = t; i < W_; i += 256) m = fmaxf(m, agg[i]);
    red[t] = m;
    __syncthreads();
    for (int s = 128; s > 0; s >>= 1) {
        if (t < s) red[t] = fmaxf(red[t], red[t + s]);
        __syncthreads();
    }
    const float mx = red[0];
    __syncthreads();
    float sum = 0.f;
    for (int i = t; i < W_; i += 256) sum += __expf(agg[i] - mx);
    red[t] = sum;
    __syncthreads();
    for (int s = 128; s > 0; s >>= 1) {
        if (t < s) red[t] += red[t + s];
        __syncthreads();
    }
    if (t == 0) { ws[0] = mx; ws[1] = red[0]; }
}

// ---------------------------------------------------------------------------
// K2: fused sliding-DFT features + reg-tiled proj GEMM + MLP per (b, chunk)
// 512 threads (8 waves). LDS ~74.5 KB -> 2 blocks/CU = 16 waves/CU.
// ---------------------------------------------------------------------------
__global__ __launch_bounds__(512, 4) void k_main(
    const float* __restrict__ x,  const float* __restrict__ pw,
    const float* __restrict__ pb, const float* __restrict__ w0g,
    const float* __restrict__ b0g,const float* __restrict__ a0g,
    const float* __restrict__ w1g,const float* __restrict__ b1g,
    const float* __restrict__ a1g,const float* __restrict__ wog,
    const float* __restrict__ bog,const float* __restrict__ agg,
    const float* __restrict__ stats, float* __restrict__ partial)
{
    // featL rows stride 516 floats: 516 % 32 == 4 -> 4 consecutive rows hit
    // 4 distinct bank-quads => conflict-free ds_read_b128.
    __shared__ __align__(16) float featL[CH_ * 516];      // 66048 B
    __shared__ __align__(16) float projL[CH_ * 36];       // 4608 B
    __shared__ __align__(16) float xtile[C_][100];        // 3200 B
    __shared__ float twc[64], tws[64];
    __shared__ float chunkAcc[CH_];

    // overlays inside featL (all dead-after-use, barriers between):
    float* pacc = featL;            // [4][32][33] = 4224 floats (16896 B)
    float* h0L  = featL;            // [32][68]    = 2176 floats (overlays dead pacc)
    float* h1L  = featL + 4224;     // [32][36]    = 1152 floats (disjoint from h0L)

    const int t     = threadIdx.x;
    const int chunk = blockIdx.x;
    const int b     = blockIdx.y;
    const int w0c   = chunk * CH_;

    // ---- stage twiddles + x tile ----
    if (t < 64) {
        float s, c;
        sincosf(6.28318530717958647692f * (float)t / 64.0f, &s, &c);
        twc[t] = c; tws[t] = s;
    }
    for (int i = t; i < C_ * 96; i += 512) {
        const int c = i / 96;
        const int j = i - c * 96;
        int gi = w0c + j; if (gi > T_ - 1) gi = T_ - 1;
        xtile[c][j] = x[((size_t)b * C_ + c) * T_ + gi];
    }
    __syncthreads();

    // ---- phase A: sliding DFT. thread = (c, f, half) ----
    {
        const int ff = t & 31;         // frequency 0..31
        const int cc = (t >> 5) & 7;   // channel 0..7
        const int hh = t >> 8;         // half 0..1 (16 w each)
        const float* xt = &xtile[cc][hh * 16];

        // seed: 64-tap DFT via 4 interleaved register-rotation chains
        const int f1 = ff, f2 = (2 * ff) & 63, f3 = (3 * ff) & 63, f4 = (4 * ff) & 63;
        float w0r = 1.f,      w0i = 0.f;
        float w1r = twc[f1],  w1i = -tws[f1];
        float w2r = twc[f2],  w2i = -tws[f2];
        float w3r = twc[f3],  w3i = -tws[f3];
        const float s4r = twc[f4], s4i = -tws[f4];
        float re = 0.f, im = 0.f;
        #pragma unroll 4
        for (int k = 0; k < 64; k += 4) {
            const float x0 = xt[k], x1 = xt[k + 1], x2 = xt[k + 2], x3 = xt[k + 3];
            re = fmaf(x0, w0r, re); im = fmaf(x0, w0i, im);
            re = fmaf(x1, w1r, re); im = fmaf(x1, w1i, im);
            re = fmaf(x2, w2r, re); im = fmaf(x2, w2i, im);
            re = fmaf(x3, w3r, re); im = fmaf(x3, w3i, im);
            float tr;
            tr = w0r * s4r - w0i * s4i; w0i = w0r * s4i + w0i * s4r; w0r = tr;
            tr = w1r * s4r - w1i * s4i; w1i = w1r * s4i + w1i * s4r; w1r = tr;
            tr = w2r * s4r - w2i * s4i; w2i = w2r * s4i + w2i * s4r; w2r = tr;
            tr = w3r * s4r - w3i * s4i; w3i = w3r * s4i + w3i * s4r; w3r = tr;
        }

        // slide 16 windows, emitting (mag, ph) each step
        const float cf = twc[ff], sf = tws[ff];
        #pragma unroll 4
        for (int wl = 0; wl < 16; ++wl) {
            const float mag = __logf(1.0f + __builtin_amdgcn_sqrtf(re * re + im * im));
            const float ph  = fast_atan2pi(im, re);
            *(float2*)&featL[(hh * 16 + wl) * 516 + cc * 64 + 2 * ff] = make_float2(mag, ph);
            const float d  = xt[wl + 64] - xt[wl];
            const float tt = re + d;
            re = tt * cf - im * sf;
            im = tt * sf + im * cf;
        }
    }
    __syncthreads();

    // ---- phase B: proj GEMM 32w x 32o, K=512, K-split 4 ----
    // thread = ks(4) x wgrp(8) x og(16); acc = 4w (w=wg+8i) x 2o (o, o+16)
    {
        const int og = t & 15;
        const int wg = (t >> 4) & 7;
        const int ks = t >> 7;
        const int o0 = og, o1 = og + 16;
        const int kb4 = ks * 32;                 // float4 offset of K-quarter

        const float4* pw4 = (const float4*)pw;
        float acc[4][2];
        #pragma unroll
        for (int i = 0; i < 4; ++i) { acc[i][0] = 0.f; acc[i][1] = 0.f; }

        #pragma unroll 4
        for (int jg = 0; jg < 32; ++jg) {
            const float4 p0 = pw4[(size_t)o0 * 128 + kb4 + jg];
            const float4 p1 = pw4[(size_t)o1 * 128 + kb4 + jg];
            #pragma unroll
            for (int i = 0; i < 4; ++i) {
                const float4 f = *(const float4*)&featL[(wg + 8 * i) * 516 + (kb4 + jg) * 4];
                acc[i][0] = fmaf(f.x, p0.x, fmaf(f.y, p0.y, fmaf(f.z, p0.z, fmaf(f.w, p0.w, acc[i][0]))));
                acc[i][1] = fmaf(f.x, p1.x, fmaf(f.y, p1.y, fmaf(f.z, p1.z, fmaf(f.w, p1.w, acc[i][1]))));
            }
        }
        __syncthreads();   // featL reads done; safe to overlay with pacc
        #pragma unroll
        for (int i = 0; i < 4; ++i) {
            pacc[(ks * 32 + wg + 8 * i) * 33 + o0] = acc[i][0];
            pacc[(ks * 32 + wg + 8 * i) * 33 + o1] = acc[i][1];
        }
    }
    __syncthreads();

    // ---- finalize proj: reduce 4 K-quarters, bias, tanh. 2 (w,o) per thread --
    {
        const int o  = t & 31;
        const int w2 = t >> 5;       // 0..15 -> handles w2 and w2+16
        const float pbv = pb[o];
        #pragma unroll
        for (int i = 0; i < 2; ++i) {
            const int w = w2 + 16 * i;
            const float s = pacc[w * 33 + o] + pacc[(32 + w) * 33 + o]
                          + pacc[(64 + w) * 33 + o] + pacc[(96 + w) * 33 + o] + pbv;
            projL[w * 36 + o] = fast_tanh(s) * PI_F;
        }
    }
    __syncthreads();

    // ---- h0 = snake(proj @ w0^T + b0): thread = (w, 4 outputs) ----
    {
        const int w  = t >> 4;
        const int ob = (t & 15) * 4;
        float4 pr[8];
        #pragma unroll
        for (int q = 0; q < 8; ++q) pr[q] = *(const float4*)&projL[w * 36 + q * 4];
        #pragma unroll
        for (int k = 0; k < 4; ++k) {
            const int o = ob + k;
            const float4* wr = (const float4*)&w0g[(size_t)o * MLP_];
            float acc = 0.f;
            #pragma unroll
            for (int q = 0; q < 8; ++q) {
                const float4 wv = wr[q];
                acc = fmaf(pr[q].x, wv.x, fmaf(pr[q].y, wv.y, fmaf(pr[q].z, wv.z, fmaf(pr[q].w, wv.w, acc))));
            }
            const float hv = acc + b0g[o];
            const float aa = fabsf(a0g[o]) + 1e-8f;
            h0L[w * 68 + o] = fast_snake(hv, fast_rcp(aa), aa);
        }
    }
    __syncthreads();

    // ---- h1 = snake(h0 @ w1^T + b1): thread = (w, 2 outputs) ----
    {
        const int w  = t >> 4;
        const int o2 = (t & 15) * 2;
        float4 hr[16];
        #pragma unroll
        for (int q = 0; q < 16; ++q) hr[q] = *(const float4*)&h0L[w * 68 + q * 4];
        #pragma unroll
        for (int k = 0; k < 2; ++k) {
            const int o = o2 + k;
            const float4* wr = (const float4*)&w1g[(size_t)o * HID_];
            float acc = 0.f;
            #pragma unroll
            for (int q = 0; q < 16; ++q) {
                const float4 wv = wr[q];
                acc = fmaf(hr[q].x, wv.x, fmaf(hr[q].y, wv.y, fmaf(hr[q].z, wv.z, fmaf(hr[q].w, wv.w, acc))));
            }
            const float hv = acc + b1g[o];
            const float aa = fabsf(a1g[o]) + 1e-8f;
            h1L[w * 36 + o] = fast_snake(hv, fast_rcp(aa), aa);
        }
    }
    __syncthreads();

    // ---- out_t + softmax weight ----
    if (t < CH_) {
        const int w = t;
        const float4* hr = (const float4*)&h1L[w * 36];
        const float4* wr = (const float4*)&wog[0];
        float acc = 0.f;
        #pragma unroll
        for (int q = 0; q < 8; ++q) {
            const float4 hv = hr[q];
            const float4 wv = wr[q];
            acc = fmaf(hv.x, wv.x, fmaf(hv.y, wv.y, fmaf(hv.z, wv.z, fmaf(hv.w, wv.w, acc))));
        }
        const float val = acc + bog[0];
        const int wg = w0c + w;
        const float sw = (wg < W_) ? __expf(agg[wg] - stats[0]) / stats[1] : 0.f;
        chunkAcc[w] = val * sw;
    }
    __syncthreads();

    // ---- reduce 32 chunk values -> 1 partial ----
    if (t < 32) {
        float vs = chunkAcc[t];
        vs += __shfl_down(vs, 16);
        vs += __shfl_down(vs, 8);
        vs += __shfl_down(vs, 4);
        vs += __shfl_down(vs, 2);
        vs += __shfl_down(vs, 1);
        if (t == 0) partial[(size_t)chunk * B_ + b] = vs;
    }
}

// ---------------------------------------------------------------------------
// K3: final reduce over chunks -> d_out[b]
// ---------------------------------------------------------------------------
__global__ void k_reduce(const float* __restrict__ partial, float* __restrict__ out)
{
    const int b = threadIdx.x;
    if (b < B_) {
        float s = 0.f;
        for (int c = 0; c < NCHUNK_; ++c) s += partial[(size_t)c * B_ + b];
        out[b] = s;
    }
}

// ---------------------------------------------------------------------------
extern "C" void kernel_launch(void* const* d_in, const int* in_sizes, int n_in,
                              void* d_out, int out_size, void* d_ws, size_t ws_size,
                              hipStream_t stream)
{
    const float* x   = (const float*)d_in[0];
    const float* pw  = (const float*)d_in[1];
    const float* pb  = (const float*)d_in[2];
    const float* w0  = (const float*)d_in[3];
    const float* b0  = (const float*)d_in[4];
    const float* a0  = (const float*)d_in[5];
    const float* w1  = (const float*)d_in[6];
    const float* b1  = (const float*)d_in[7];
    const float* a1  = (const float*)d_in[8];
    const float* wo  = (const float*)d_in[9];
    const float* bo  = (const float*)d_in[10];
    const float* agg = (const float*)d_in[11];
    float* ws  = (float*)d_ws;
    float* out = (float*)d_out;

    k_softmax_stats<<<1, 256, 0, stream>>>(agg, ws);
    dim3 grid(NCHUNK_, B_);
    k_main<<<grid, 512, 0, stream>>>(x, pw, pb, w0, b0, a0, w1, b1, a1, wo, bo,
                                     agg, ws, ws + 2);
    k_reduce<<<1, 64, 0, stream>>>(ws + 2, out);
}

// Round 4
// 477.872 us; speedup vs baseline: 2.7748x; 1.0125x over previous
//
#include <hip/hip_runtime.h>
#include <math.h>

#define B_ 64
#define C_ 8
#define T_ 2048
#define K_ 64
#define NF_ 32
#define FFT_DIM_ 512
#define MLP_ 32
#define HID_ 64
#define W_ 1985
#define CH_ 32
#define NCHUNK_ 63   /* ceil(1985/32) */
#define PI_F 3.14159265358979323846f

// ---------------- fast inline transcendentals (branchless) ----------------
__device__ __forceinline__ float fast_rcp(float x) { return __builtin_amdgcn_rcpf(x); }

// atan2(y,x)/pi, max err ~1e-6.
__device__ __forceinline__ float fast_atan2pi(float y, float x)
{
    const float ax = fabsf(x), ay = fabsf(y);
    const float mx = fmaxf(ax, ay), mn = fminf(ax, ay);
    const float r  = mn * fast_rcp(fmaxf(mx, 1e-30f));
    const float t  = r * r;
    float a = -0.003730950f;
    a = fmaf(a, t,  0.016759940f);
    a = fmaf(a, t, -0.037059946f);
    a = fmaf(a, t,  0.061602941f);
    a = fmaf(a, t, -0.105877528f);
    a = fmaf(a, t,  0.318302656f);
    a *= r;
    a = (ay > ax) ? (0.5f - a) : a;
    a = (x < 0.0f) ? (1.0f - a) : a;
    return copysignf(a, y);
}

__device__ __forceinline__ float fast_tanh(float x)
{
    const float e = __expf(2.0f * x);
    return 1.0f - 2.0f * fast_rcp(e + 1.0f);
}

__device__ __forceinline__ float fast_snake(float h, float rcp_aa, float aa)
{
    const float s = __sinf(aa * h);
    return h + s * s * rcp_aa;
}

// ---------------------------------------------------------------------------
// K1: softmax stats over agg (W,) -> ws[0]=max, ws[1]=sum(exp(agg-max))
// ---------------------------------------------------------------------------
__global__ __launch_bounds__(256) void k_softmax_stats(
    const float* __restrict__ agg, float* __restrict__ ws)
{
    __shared__ float red[256];
    const int t = threadIdx.x;
    float m = -1e30f;
    for (int i = t; i < W_; i += 256) m = fmaxf(m, agg[i]);
    red[t] = m;
    __syncthreads();
    for (int s = 128; s > 0; s >>= 1) {
        if (t < s) red[t] = fmaxf(red[t], red[t + s]);
        __syncthreads();
    }
    const float mx = red[0];
    __syncthreads();
    float sum = 0.f;
    for (int i = t; i < W_; i += 256) sum += __expf(agg[i] - mx);
    red[t] = sum;
    __syncthreads();
    for (int s = 128; s > 0; s >>= 1) {
        if (t < s) red[t] += red[t + s];
        __syncthreads();
    }
    if (t == 0) { ws[0] = mx; ws[1] = red[0]; }
}

// ---------------------------------------------------------------------------
// K2: fused sliding-DFT features + reg-tiled proj GEMM + MLP per (b, chunk)
// 1024 threads (16 waves), LDS ~74.5 KB -> 2 blocks/CU = 32 waves/CU (8/SIMD).
// ---------------------------------------------------------------------------
__global__ __launch_bounds__(1024, 8) void k_main(
    const float* __restrict__ x,  const float* __restrict__ pw,
    const float* __restrict__ pb, const float* __restrict__ w0g,
    const float* __restrict__ b0g,const float* __restrict__ a0g,
    const float* __restrict__ w1g,const float* __restrict__ b1g,
    const float* __restrict__ a1g,const float* __restrict__ wog,
    const float* __restrict__ bog,const float* __restrict__ agg,
    const float* __restrict__ stats, float* __restrict__ partial)
{
    // featL rows stride 516 floats (rows 16B-aligned, 516%32==4 -> adjacent
    // rows land on distinct bank-quads; broadcast groups within waves).
    __shared__ __align__(16) float featL[CH_ * 516];      // 66048 B
    __shared__ __align__(16) float projL[CH_ * 36];       // 4608 B
    __shared__ __align__(16) float xtile[C_][100];        // 3200 B
    __shared__ float twc[64], tws[64];
    __shared__ float chunkAcc[CH_];

    // overlays inside featL (dead-after-use, barriers between):
    float* pacc = featL;            // [8][32][33] = 8448 floats (33792 B)
    float* h0L  = featL;            // [32][68]    = 2176 floats (overlays dead pacc)
    float* h1L  = featL + 8448;     // [32][36]    = 1152 floats (disjoint)

    const int t     = threadIdx.x;
    const int chunk = blockIdx.x;
    const int b     = blockIdx.y;
    const int w0c   = chunk * CH_;

    // ---- stage twiddles + x tile ----
    if (t < 64) {
        float s, c;
        sincosf(6.28318530717958647692f * (float)t / 64.0f, &s, &c);
        twc[t] = c; tws[t] = s;
    }
    if (t < C_ * 96) {
        const int c = t / 96;
        const int j = t - c * 96;
        int gi = w0c + j; if (gi > T_ - 1) gi = T_ - 1;
        xtile[c][j] = x[((size_t)b * C_ + c) * T_ + gi];
    }
    __syncthreads();

    // ---- phase A: sliding DFT. thread = (quarter hh, channel cc, freq ff) ----
    {
        const int ff = t & 31;         // frequency 0..31
        const int cc = (t >> 5) & 7;   // channel 0..7
        const int hh = t >> 8;         // quarter 0..3 (8 w each)
        const float* xt = &xtile[cc][hh * 8];
        const float4* xt4 = (const float4*)xt;   // hh*8 floats = 32B aligned

        // seed: 64-tap DFT via 4 interleaved register-rotation chains
        const int f1 = ff, f2 = (2 * ff) & 63, f3 = (3 * ff) & 63, f4 = (4 * ff) & 63;
        float w0r = 1.f,      w0i = 0.f;
        float w1r = twc[f1],  w1i = -tws[f1];
        float w2r = twc[f2],  w2i = -tws[f2];
        float w3r = twc[f3],  w3i = -tws[f3];
        const float s4r = twc[f4], s4i = -tws[f4];
        float re = 0.f, im = 0.f;
        #pragma unroll 4
        for (int k4 = 0; k4 < 16; ++k4) {
            const float4 xv = xt4[k4];
            re = fmaf(xv.x, w0r, re); im = fmaf(xv.x, w0i, im);
            re = fmaf(xv.y, w1r, re); im = fmaf(xv.y, w1i, im);
            re = fmaf(xv.z, w2r, re); im = fmaf(xv.z, w2i, im);
            re = fmaf(xv.w, w3r, re); im = fmaf(xv.w, w3i, im);
            float tr;
            tr = w0r * s4r - w0i * s4i; w0i = w0r * s4i + w0i * s4r; w0r = tr;
            tr = w1r * s4r - w1i * s4i; w1i = w1r * s4i + w1i * s4r; w1r = tr;
            tr = w2r * s4r - w2i * s4i; w2i = w2r * s4i + w2i * s4r; w2r = tr;
            tr = w3r * s4r - w3i * s4i; w3i = w3r * s4i + w3i * s4r; w3r = tr;
        }

        // slide 8 windows, emitting (mag, ph) each step; float4 tap reads
        const float cf = twc[ff], sf = tws[ff];
        #pragma unroll
        for (int g = 0; g < 2; ++g) {
            const float4 lo = *(const float4*)&xt[g * 4];
            const float4 hi = *(const float4*)&xt[g * 4 + 64];
            const float dl[4] = { hi.x - lo.x, hi.y - lo.y, hi.z - lo.z, hi.w - lo.w };
            #pragma unroll
            for (int j = 0; j < 4; ++j) {
                const float mag = __logf(1.0f + __builtin_amdgcn_sqrtf(re * re + im * im));
                const float ph  = fast_atan2pi(im, re);
                *(float2*)&featL[(hh * 8 + g * 4 + j) * 516 + cc * 64 + 2 * ff] =
                    make_float2(mag, ph);
                const float tt = re + dl[j];
                re = tt * cf - im * sf;
                im = tt * sf + im * cf;
            }
        }
    }
    __syncthreads();

    // ---- phase B: proj GEMM 32w x 32o, K=512, K-split 8 ----
    // thread = ks(8) x wg(8) x og(16); acc = 4w (w=wg+8i) x 2o (o, o+16)
    {
        const int og = t & 15;
        const int wg = (t >> 4) & 7;
        const int ks = t >> 7;           // 0..7
        const int o0 = og, o1 = og + 16;
        const int kb4 = ks * 16;         // float4 offset of K-eighth

        const float4* pw4 = (const float4*)pw;
        float acc[4][2];
        #pragma unroll
        for (int i = 0; i < 4; ++i) { acc[i][0] = 0.f; acc[i][1] = 0.f; }

        #pragma unroll 4
        for (int jg = 0; jg < 16; ++jg) {
            const float4 p0 = pw4[(size_t)o0 * 128 + kb4 + jg];
            const float4 p1 = pw4[(size_t)o1 * 128 + kb4 + jg];
            #pragma unroll
            for (int i = 0; i < 4; ++i) {
                const float4 f = *(const float4*)&featL[(wg + 8 * i) * 516 + (kb4 + jg) * 4];
                acc[i][0] = fmaf(f.x, p0.x, fmaf(f.y, p0.y, fmaf(f.z, p0.z, fmaf(f.w, p0.w, acc[i][0]))));
                acc[i][1] = fmaf(f.x, p1.x, fmaf(f.y, p1.y, fmaf(f.z, p1.z, fmaf(f.w, p1.w, acc[i][1]))));
            }
        }
        __syncthreads();   // featL reads done; safe to overlay with pacc
        #pragma unroll
        for (int i = 0; i < 4; ++i) {
            pacc[(ks * 32 + wg + 8 * i) * 33 + o0] = acc[i][0];
            pacc[(ks * 32 + wg + 8 * i) * 33 + o1] = acc[i][1];
        }
    }
    __syncthreads();

    // ---- finalize proj: reduce 8 K-eighths, bias, tanh. 1 (w,o)/thread ----
    {
        const int o = t & 31;
        const int w = t >> 5;
        float s = pb[o];
        #pragma unroll
        for (int q = 0; q < 8; ++q) s += pacc[(q * 32 + w) * 33 + o];
        projL[w * 36 + o] = fast_tanh(s) * PI_F;
    }
    __syncthreads();

    // ---- h0 = snake(proj @ w0^T + b0): thread = (w, 2 outputs) ----
    {
        const int w  = t >> 5;
        const int o2 = (t & 31) * 2;
        float4 pr[8];
        #pragma unroll
        for (int q = 0; q < 8; ++q) pr[q] = *(const float4*)&projL[w * 36 + q * 4];
        #pragma unroll
        for (int k = 0; k < 2; ++k) {
            const int o = o2 + k;
            const float4* wr = (const float4*)&w0g[(size_t)o * MLP_];
            float acc = 0.f;
            #pragma unroll
            for (int q = 0; q < 8; ++q) {
                const float4 wv = wr[q];
                acc = fmaf(pr[q].x, wv.x, fmaf(pr[q].y, wv.y, fmaf(pr[q].z, wv.z, fmaf(pr[q].w, wv.w, acc))));
            }
            const float hv = acc + b0g[o];
            const float aa = fabsf(a0g[o]) + 1e-8f;
            h0L[w * 68 + o] = fast_snake(hv, fast_rcp(aa), aa);
        }
    }
    __syncthreads();

    // ---- h1 = snake(h0 @ w1^T + b1): thread = (w, 1 output), streamed ----
    {
        const int w = t >> 5;
        const int o = t & 31;
        const float4* hr = (const float4*)&h0L[w * 68];
        const float4* wr = (const float4*)&w1g[(size_t)o * HID_];
        float acc = 0.f;
        #pragma unroll 4
        for (int q = 0; q < 16; ++q) {
            const float4 hv = hr[q];
            const float4 wv = wr[q];
            acc = fmaf(hv.x, wv.x, fmaf(hv.y, wv.y, fmaf(hv.z, wv.z, fmaf(hv.w, wv.w, acc))));
        }
        const float hv = acc + b1g[o];
        const float aa = fabsf(a1g[o]) + 1e-8f;
        h1L[w * 36 + o] = fast_snake(hv, fast_rcp(aa), aa);
    }
    __syncthreads();

    // ---- out_t + softmax weight ----
    if (t < CH_) {
        const int w = t;
        const float4* hr = (const float4*)&h1L[w * 36];
        const float4* wr = (const float4*)&wog[0];
        float acc = 0.f;
        #pragma unroll
        for (int q = 0; q < 8; ++q) {
            const float4 hv = hr[q];
            const float4 wv = wr[q];
            acc = fmaf(hv.x, wv.x, fmaf(hv.y, wv.y, fmaf(hv.z, wv.z, fmaf(hv.w, wv.w, acc))));
        }
        const float val = acc + bog[0];
        const int wg = w0c + w;
        const float sw = (wg < W_) ? __expf(agg[wg] - stats[0]) / stats[1] : 0.f;
        chunkAcc[w] = val * sw;
    }
    __syncthreads();

    // ---- reduce 32 chunk values -> 1 partial ----
    if (t < 32) {
        float vs = chunkAcc[t];
        vs += __shfl_down(vs, 16);
        vs += __shfl_down(vs, 8);
        vs += __shfl_down(vs, 4);
        vs += __shfl_down(vs, 2);
        vs += __shfl_down(vs, 1);
        if (t == 0) partial[(size_t)chunk * B_ + b] = vs;
    }
}

// ---------------------------------------------------------------------------
// K3: final reduce over chunks -> d_out[b]
// ---------------------------------------------------------------------------
__global__ void k_reduce(const float* __restrict__ partial, float* __restrict__ out)
{
    const int b = threadIdx.x;
    if (b < B_) {
        float s = 0.f;
        for (int c = 0; c < NCHUNK_; ++c) s += partial[(size_t)c * B_ + b];
        out[b] = s;
    }
}

// ---------------------------------------------------------------------------
extern "C" void kernel_launch(void* const* d_in, const int* in_sizes, int n_in,
                              void* d_out, int out_size, void* d_ws, size_t ws_size,
                              hipStream_t stream)
{
    const float* x   = (const float*)d_in[0];
    const float* pw  = (const float*)d_in[1];
    const float* pb  = (const float*)d_in[2];
    const float* w0  = (const float*)d_in[3];
    const float* b0  = (const float*)d_in[4];
    const float* a0  = (const float*)d_in[5];
    const float* w1  = (const float*)d_in[6];
    const float* b1  = (const float*)d_in[7];
    const float* a1  = (const float*)d_in[8];
    const float* wo  = (const float*)d_in[9];
    const float* bo  = (const float*)d_in[10];
    const float* agg = (const float*)d_in[11];
    float* ws  = (float*)d_ws;
    float* out = (float*)d_out;

    k_softmax_stats<<<1, 256, 0, stream>>>(agg, ws);
    dim3 grid(NCHUNK_, B_);
    k_main<<<grid, 1024, 0, stream>>>(x, pw, pb, w0, b0, a0, w1, b1, a1, wo, bo,
                                      agg, ws, ws + 2);
    k_reduce<<<1, 64, 0, stream>>>(ws + 2, out);
}

// Round 5
// 258.614 us; speedup vs baseline: 5.1274x; 1.8478x over previous
//
#include <hip/hip_runtime.h>
#include <math.h>

#define B_ 64
#define C_ 8
#define T_ 2048
#define K_ 64
#define NF_ 32
#define FFT_DIM_ 512
#define MLP_ 32
#define HID_ 64
#define W_ 1985
#define CH_ 32
#define NCHUNK_ 63   /* ceil(1985/32) */
#define PI_F 3.14159265358979323846f

// ---------------- fast inline transcendentals (branchless) ----------------
__device__ __forceinline__ float fast_rcp(float x) { return __builtin_amdgcn_rcpf(x); }

// atan2(y,x)/pi, max err ~1e-6.
__device__ __forceinline__ float fast_atan2pi(float y, float x)
{
    const float ax = fabsf(x), ay = fabsf(y);
    const float mx = fmaxf(ax, ay), mn = fminf(ax, ay);
    const float r  = mn * fast_rcp(fmaxf(mx, 1e-30f));
    const float t  = r * r;
    float a = -0.003730950f;
    a = fmaf(a, t,  0.016759940f);
    a = fmaf(a, t, -0.037059946f);
    a = fmaf(a, t,  0.061602941f);
    a = fmaf(a, t, -0.105877528f);
    a = fmaf(a, t,  0.318302656f);
    a *= r;
    a = (ay > ax) ? (0.5f - a) : a;
    a = (x < 0.0f) ? (1.0f - a) : a;
    return copysignf(a, y);
}

__device__ __forceinline__ float fast_tanh(float x)
{
    const float e = __expf(2.0f * x);
    return 1.0f - 2.0f * fast_rcp(e + 1.0f);
}

__device__ __forceinline__ float fast_snake(float h, float rcp_aa, float aa)
{
    const float s = __sinf(aa * h);
    return h + s * s * rcp_aa;
}

__device__ __forceinline__ float dot4(float4 a, float4 b, float acc)
{
    return fmaf(a.x, b.x, fmaf(a.y, b.y, fmaf(a.z, b.z, fmaf(a.w, b.w, acc))));
}

// ---------------------------------------------------------------------------
// K1: softmax stats over agg (W,) -> ws[0]=max, ws[1]=sum(exp(agg-max))
// ---------------------------------------------------------------------------
__global__ __launch_bounds__(256) void k_softmax_stats(
    const float* __restrict__ agg, float* __restrict__ ws)
{
    __shared__ float red[256];
    const int t = threadIdx.x;
    float m = -1e30f;
    for (int i = t; i < W_; i += 256) m = fmaxf(m, agg[i]);
    red[t] = m;
    __syncthreads();
    for (int s = 128; s > 0; s >>= 1) {
        if (t < s) red[t] = fmaxf(red[t], red[t + s]);
        __syncthreads();
    }
    const float mx = red[0];
    __syncthreads();
    float sum = 0.f;
    for (int i = t; i < W_; i += 256) sum += __expf(agg[i] - mx);
    red[t] = sum;
    __syncthreads();
    for (int s = 128; s > 0; s >>= 1) {
        if (t < s) red[t] += red[t + s];
        __syncthreads();
    }
    if (t == 0) { ws[0] = mx; ws[1] = red[0]; }
}

// ---------------------------------------------------------------------------
// K2: fused sliding-DFT + all-LDS proj GEMM + MLP per (b, chunk).
// 1024 threads (16 waves), LDS ~158 KB -> 1 block/CU (16 waves/CU).
// All weights staged to LDS (pw async over phase A); inner loops LDS-only.
// ---------------------------------------------------------------------------
__global__ __launch_bounds__(1024, 4) void k_main(
    const float* __restrict__ x,  const float* __restrict__ pw,
    const float* __restrict__ pb, const float* __restrict__ w0g,
    const float* __restrict__ b0g,const float* __restrict__ a0g,
    const float* __restrict__ w1g,const float* __restrict__ b1g,
    const float* __restrict__ a1g,const float* __restrict__ wog,
    const float* __restrict__ bog,const float* __restrict__ agg,
    const float* __restrict__ stats, float* __restrict__ partial)
{
    __shared__ __align__(16) float featL[CH_ * 512];   // 65536 B (k4 XOR-swizzled)
    __shared__ __align__(16) float pwL[32 * 512];      // 65536 B (k4 XOR-swizzled)
    __shared__ __align__(16) float w0L[64 * 36];       // 9216 B
    __shared__ __align__(16) float w1L[32 * 68];       // 8704 B
    __shared__ __align__(16) float projL[CH_ * 36];    // 4608 B
    __shared__ __align__(16) float xtile[C_][100];     // 3200 B
    __shared__ float twc[64], tws[64];
    __shared__ float smalls[260];   // [0..31]=pb [32..95]=b0 [96..159]=a0
                                    // [160..191]=b1 [192..223]=a1 [224..255]=wo [256]=bo
    __shared__ float chunkAcc[CH_];

    // overlays inside featL (dead-after-use, barriers between):
    float* pacc = featL;            // [16][32][32] = 16384 floats (exact fit)
    float* h0L  = featL;            // [32][68] = 2176 floats (after pacc dead)
    float* h1L  = featL + 2176;     // [32][36] = 1152 floats (disjoint)

    const int t     = threadIdx.x;
    const int chunk = blockIdx.x;
    const int b     = blockIdx.y;
    const int w0c   = chunk * CH_;

    // ======== T14 issue-early: global loads for LDS-staged weights ========
    float4 pwr[4];
    {
        const float4* pw4 = (const float4*)pw;
        #pragma unroll
        for (int r = 0; r < 4; ++r) pwr[r] = pw4[t * 4 + r];   // q = t*4+r
    }
    float4 w0r, w1r;
    if (t < 512) {
        w0r = ((const float4*)w0g)[t];
        w1r = ((const float4*)w1g)[t];
    }
    float smv = 0.f;
    if (t < 257) {
        if      (t <  32) smv = pb[t];
        else if (t <  96) smv = b0g[t - 32];
        else if (t < 160) smv = a0g[t - 96];
        else if (t < 192) smv = b1g[t - 160];
        else if (t < 224) smv = a1g[t - 192];
        else if (t < 256) smv = wog[t - 224];
        else              smv = bog[0];
    }

    // ---- stage twiddles + x tile ----
    if (t < 64) {
        float s, c;
        sincosf(6.28318530717958647692f * (float)t / 64.0f, &s, &c);
        twc[t] = c; tws[t] = s;
    }
    if (t < C_ * 96) {
        const int c = t / 96;
        const int j = t - c * 96;
        int gi = w0c + j; if (gi > T_ - 1) gi = T_ - 1;
        xtile[c][j] = x[((size_t)b * C_ + c) * T_ + gi];
    }
    __syncthreads();

    // ---- phase A: sliding DFT. thread = (quarter hh, channel cc, freq ff) ----
    {
        const int ff = t & 31;         // frequency 0..31
        const int cc = (t >> 5) & 7;   // channel 0..7
        const int hh = t >> 8;         // quarter 0..3 (8 w each)
        const float* xt = &xtile[cc][hh * 8];
        const float4* xt4 = (const float4*)xt;

        // seed: 64-tap DFT via 4 interleaved register-rotation chains
        const int f1 = ff, f2 = (2 * ff) & 63, f3 = (3 * ff) & 63, f4 = (4 * ff) & 63;
        float w0a = 1.f,      w0i = 0.f;
        float w1a = twc[f1],  w1i = -tws[f1];
        float w2a = twc[f2],  w2i = -tws[f2];
        float w3a = twc[f3],  w3i = -tws[f3];
        const float s4r = twc[f4], s4i = -tws[f4];
        float re = 0.f, im = 0.f;
        #pragma unroll 4
        for (int k4i = 0; k4i < 16; ++k4i) {
            const float4 xv = xt4[k4i];
            re = fmaf(xv.x, w0a, re); im = fmaf(xv.x, w0i, im);
            re = fmaf(xv.y, w1a, re); im = fmaf(xv.y, w1i, im);
            re = fmaf(xv.z, w2a, re); im = fmaf(xv.z, w2i, im);
            re = fmaf(xv.w, w3a, re); im = fmaf(xv.w, w3i, im);
            float tr;
            tr = w0a * s4r - w0i * s4i; w0i = w0a * s4i + w0i * s4r; w0a = tr;
            tr = w1a * s4r - w1i * s4i; w1i = w1a * s4i + w1i * s4r; w1a = tr;
            tr = w2a * s4r - w2i * s4i; w2i = w2a * s4i + w2i * s4r; w2a = tr;
            tr = w3a * s4r - w3i * s4i; w3i = w3a * s4i + w3i * s4r; w3a = tr;
        }

        // slide 8 windows, emitting (mag, ph); featL write k4-XOR-swizzled
        const float cf = twc[ff], sf = tws[ff];
        const int k4 = cc * 16 + (ff >> 1);
        const int sub = 2 * (ff & 1);
        #pragma unroll
        for (int g = 0; g < 2; ++g) {
            const float4 lo = *(const float4*)&xt[g * 4];
            const float4 hi = *(const float4*)&xt[g * 4 + 64];
            const float dl[4] = { hi.x - lo.x, hi.y - lo.y, hi.z - lo.z, hi.w - lo.w };
            #pragma unroll
            for (int j = 0; j < 4; ++j) {
                const float mag = __logf(1.0f + __builtin_amdgcn_sqrtf(re * re + im * im));
                const float ph  = fast_atan2pi(im, re);
                const int wrow = hh * 8 + g * 4 + j;
                const int k4s = k4 ^ (wrow & 7);
                *(float2*)&featL[wrow * 512 + k4s * 4 + sub] = make_float2(mag, ph);
                const float tt = re + dl[j];
                re = tt * cf - im * sf;
                im = tt * sf + im * cf;
            }
        }
    }

    // ======== T14 write-late: drain staged regs into LDS ========
    {
        #pragma unroll
        for (int r = 0; r < 4; ++r) {
            const int q  = t * 4 + r;          // (o, k4) flat
            const int o  = q >> 7;
            const int k4 = q & 127;
            *(float4*)&pwL[o * 512 + ((k4 ^ (o & 7)) * 4)] = pwr[r];
        }
        if (t < 512) {
            const int o0 = t >> 3, k40 = t & 7;        // w0: 64 rows x 8 f4
            *(float4*)&w0L[o0 * 36 + k40 * 4] = w0r;
            const int o1 = t >> 4, k41 = t & 15;       // w1: 32 rows x 16 f4
            *(float4*)&w1L[o1 * 68 + k41 * 4] = w1r;
        }
        if (t < 257) smalls[t] = smv;
    }
    __syncthreads();

    // ---- phase B: proj GEMM 32w x 32o, K=512, all-LDS, acc[4][4] ----
    // thread = ks(16) x wg(8) x og(8); w = wg+8i, o = og+8j
    {
        const int og = t & 7;
        const int wg = (t >> 3) & 7;
        const int ks = t >> 6;            // 0..15
        float acc[4][4];
        #pragma unroll
        for (int i = 0; i < 4; ++i)
            #pragma unroll
            for (int j = 0; j < 4; ++j) acc[i][j] = 0.f;

        #pragma unroll
        for (int jg = 0; jg < 8; ++jg) {
            const int k4 = ks * 8 + jg;
            float4 f[4], p[4];
            #pragma unroll
            for (int i = 0; i < 4; ++i)
                f[i] = *(const float4*)&featL[(wg + 8 * i) * 512 + ((k4 ^ wg) * 4)];
            #pragma unroll
            for (int j = 0; j < 4; ++j)
                p[j] = *(const float4*)&pwL[(og + 8 * j) * 512 + ((k4 ^ og) * 4)];
            #pragma unroll
            for (int i = 0; i < 4; ++i)
                #pragma unroll
                for (int j = 0; j < 4; ++j)
                    acc[i][j] = dot4(f[i], p[j], acc[i][j]);
        }
        __syncthreads();   // featL reads done; overlay with pacc
        #pragma unroll
        for (int i = 0; i < 4; ++i) {
            #pragma unroll
            for (int j = 0; j < 4; ++j) {
                const int w = wg + 8 * i, o = og + 8 * j;
                pacc[ks * 1024 + w * 32 + (o ^ ((w & 7) << 2))] = acc[i][j];
            }
        }
    }
    __syncthreads();

    // ---- finalize proj: reduce 16 K-slices, bias, tanh. 1 (w,o)/thread ----
    {
        const int o = t & 31;
        const int w = t >> 5;
        const int oS = o ^ ((w & 7) << 2);
        float s = smalls[o];               // pb
        #pragma unroll
        for (int q = 0; q < 16; ++q) s += pacc[q * 1024 + w * 32 + oS];
        projL[w * 36 + o] = fast_tanh(s) * PI_F;
    }
    __syncthreads();

    // ---- h0 = snake(proj @ w0^T + b0): thread = (w, 2 outputs), all-LDS ----
    {
        const int w  = t >> 5;
        const int o2 = (t & 31) * 2;
        float4 pr[8];
        #pragma unroll
        for (int q = 0; q < 8; ++q) pr[q] = *(const float4*)&projL[w * 36 + q * 4];
        float hv2[2];
        #pragma unroll
        for (int k = 0; k < 2; ++k) {
            const int o = o2 + k;
            float acc = 0.f;
            #pragma unroll
            for (int q = 0; q < 8; ++q)
                acc = dot4(pr[q], *(const float4*)&w0L[o * 36 + q * 4], acc);
            const float hv = acc + smalls[32 + o];
            const float aa = fabsf(smalls[96 + o]) + 1e-8f;
            hv2[k] = fast_snake(hv, fast_rcp(aa), aa);
        }
        __syncthreads();   // pacc fully dead before h0L overlay
        h0L[w * 68 + o2]     = hv2[0];
        h0L[w * 68 + o2 + 1] = hv2[1];
    }
    __syncthreads();

    // ---- h1 = snake(h0 @ w1^T + b1): thread = (w, 1 output), all-LDS ----
    {
        const int w = t >> 5;
        const int o = t & 31;
        float acc = 0.f;
        #pragma unroll 4
        for (int q = 0; q < 16; ++q)
            acc = dot4(*(const float4*)&h0L[w * 68 + q * 4],
                       *(const float4*)&w1L[o * 68 + q * 4], acc);
        const float hv = acc + smalls[160 + o];
        const float aa = fabsf(smalls[192 + o]) + 1e-8f;
        h1L[w * 36 + o] = fast_snake(hv, fast_rcp(aa), aa);
    }
    __syncthreads();

    // ---- out_t + softmax weight ----
    if (t < CH_) {
        const int w = t;
        float acc = 0.f;
        #pragma unroll
        for (int q = 0; q < 8; ++q)
            acc = dot4(*(const float4*)&h1L[w * 36 + q * 4],
                       *(const float4*)&smalls[224 + q * 4], acc);
        const float val = acc + smalls[256];
        const int wg = w0c + w;
        const float sw = (wg < W_) ? __expf(agg[wg] - stats[0]) / stats[1] : 0.f;
        chunkAcc[w] = val * sw;
    }
    __syncthreads();

    // ---- reduce 32 chunk values -> 1 partial ----
    if (t < 32) {
        float vs = chunkAcc[t];
        vs += __shfl_down(vs, 16);
        vs += __shfl_down(vs, 8);
        vs += __shfl_down(vs, 4);
        vs += __shfl_down(vs, 2);
        vs += __shfl_down(vs, 1);
        if (t == 0) partial[(size_t)chunk * B_ + b] = vs;
    }
}

// ---------------------------------------------------------------------------
// K3: final reduce over chunks -> d_out[b]
// ---------------------------------------------------------------------------
__global__ void k_reduce(const float* __restrict__ partial, float* __restrict__ out)
{
    const int b = threadIdx.x;
    if (b < B_) {
        float s = 0.f;
        for (int c = 0; c < NCHUNK_; ++c) s += partial[(size_t)c * B_ + b];
        out[b] = s;
    }
}

// ---------------------------------------------------------------------------
extern "C" void kernel_launch(void* const* d_in, const int* in_sizes, int n_in,
                              void* d_out, int out_size, void* d_ws, size_t ws_size,
                              hipStream_t stream)
{
    const float* x   = (const float*)d_in[0];
    const float* pw  = (const float*)d_in[1];
    const float* pb  = (const float*)d_in[2];
    const float* w0  = (const float*)d_in[3];
    const float* b0  = (const float*)d_in[4];
    const float* a0  = (const float*)d_in[5];
    const float* w1  = (const float*)d_in[6];
    const float* b1  = (const float*)d_in[7];
    const float* a1  = (const float*)d_in[8];
    const float* wo  = (const float*)d_in[9];
    const float* bo  = (const float*)d_in[10];
    const float* agg = (const float*)d_in[11];
    float* ws  = (float*)d_ws;
    float* out = (float*)d_out;

    k_softmax_stats<<<1, 256, 0, stream>>>(agg, ws);
    dim3 grid(NCHUNK_, B_);
    k_main<<<grid, 1024, 0, stream>>>(x, pw, pb, w0, b0, a0, w1, b1, a1, wo, bo,
                                      agg, ws, ws + 2);
    k_reduce<<<1, 64, 0, stream>>>(ws + 2, out);
}

// Round 6
// 223.297 us; speedup vs baseline: 5.9384x; 1.1582x over previous
//
#include <hip/hip_runtime.h>
#include <math.h>

#define B_ 64
#define C_ 8
#define T_ 2048
#define K_ 64
#define NF_ 32
#define FFT_DIM_ 512
#define MLP_ 32
#define HID_ 64
#define W_ 1985
#define CH_ 32
#define NCHUNK_ 63   /* ceil(1985/32) */
#define PI_F 3.14159265358979323846f

// ---------------- fast inline transcendentals (branchless) ----------------
__device__ __forceinline__ float fast_rcp(float x) { return __builtin_amdgcn_rcpf(x); }

// atan2(y,x)/pi, max err ~1e-6.
__device__ __forceinline__ float fast_atan2pi(float y, float x)
{
    const float ax = fabsf(x), ay = fabsf(y);
    const float mx = fmaxf(ax, ay), mn = fminf(ax, ay);
    const float r  = mn * fast_rcp(fmaxf(mx, 1e-30f));
    const float t  = r * r;
    float a = -0.003730950f;
    a = fmaf(a, t,  0.016759940f);
    a = fmaf(a, t, -0.037059946f);
    a = fmaf(a, t,  0.061602941f);
    a = fmaf(a, t, -0.105877528f);
    a = fmaf(a, t,  0.318302656f);
    a *= r;
    a = (ay > ax) ? (0.5f - a) : a;
    a = (x < 0.0f) ? (1.0f - a) : a;
    return copysignf(a, y);
}

__device__ __forceinline__ float fast_tanh(float x)
{
    const float e = __expf(2.0f * x);
    return 1.0f - 2.0f * fast_rcp(e + 1.0f);
}

__device__ __forceinline__ float fast_snake(float h, float rcp_aa, float aa)
{
    const float s = __sinf(aa * h);
    return h + s * s * rcp_aa;
}

__device__ __forceinline__ float dot4(float4 a, float4 b, float acc)
{
    return fmaf(a.x, b.x, fmaf(a.y, b.y, fmaf(a.z, b.z, fmaf(a.w, b.w, acc))));
}

// async global->LDS, 16B per lane; dest = wave-uniform base + lane*16
__device__ __forceinline__ void gload_lds16(const float* g, float* l)
{
    __builtin_amdgcn_global_load_lds(
        (const __attribute__((address_space(1))) void*)g,
        (__attribute__((address_space(3))) void*)l, 16, 0, 0);
}

// ---------------------------------------------------------------------------
// K1: softmax stats over agg (W,) -> ws[0]=max, ws[1]=sum(exp(agg-max))
// ---------------------------------------------------------------------------
__global__ __launch_bounds__(256) void k_softmax_stats(
    const float* __restrict__ agg, float* __restrict__ ws)
{
    __shared__ float red[256];
    const int t = threadIdx.x;
    float m = -1e30f;
    for (int i = t; i < W_; i += 256) m = fmaxf(m, agg[i]);
    red[t] = m;
    __syncthreads();
    for (int s = 128; s > 0; s >>= 1) {
        if (t < s) red[t] = fmaxf(red[t], red[t + s]);
        __syncthreads();
    }
    const float mx = red[0];
    __syncthreads();
    float sum = 0.f;
    for (int i = t; i < W_; i += 256) sum += __expf(agg[i] - mx);
    red[t] = sum;
    __syncthreads();
    for (int s = 128; s > 0; s >>= 1) {
        if (t < s) red[t] += red[t + s];
        __syncthreads();
    }
    if (t == 0) { ws[0] = mx; ws[1] = red[0]; }
}

// ---------------------------------------------------------------------------
// K2: fused sliding-DFT + all-LDS proj GEMM + MLP per (b, chunk).
// 1024 threads (16 waves), LDS ~155 KB -> 1 block/CU.
// pw staged via async global_load_lds (hidden under phase A, zero VGPR).
// ---------------------------------------------------------------------------
__global__ __launch_bounds__(1024) void k_main(
    const float* __restrict__ x,  const float* __restrict__ pw,
    const float* __restrict__ pb, const float* __restrict__ w0g,
    const float* __restrict__ b0g,const float* __restrict__ a0g,
    const float* __restrict__ w1g,const float* __restrict__ b1g,
    const float* __restrict__ a1g,const float* __restrict__ wog,
    const float* __restrict__ bog,const float* __restrict__ agg,
    const float* __restrict__ stats, float* __restrict__ partial)
{
    __shared__ __align__(16) float featL[CH_ * 512];   // 65536 B (k4 XOR-swizzled)
    __shared__ __align__(16) float pwL[32 * 512];      // 65536 B (k4 XOR-swizzled)
    __shared__ __align__(16) float w0L[64 * 36];       // 9216 B
    __shared__ __align__(16) float w1L[32 * 68];       // 8704 B
    __shared__ __align__(16) float projL[CH_ * 36];    // 4608 B
    __shared__ __align__(16) float xtile[C_][100];     // 3200 B
    __shared__ float twc[64], tws[64];
    __shared__ float smalls[260];   // [0..31]=pb [32..95]=b0 [96..159]=a0
                                    // [160..191]=b1 [192..223]=a1 [224..255]=wo [256]=bo
    __shared__ float chunkAcc[CH_];

    // overlays inside featL (dead-after-use, barriers between):
    float* pacc = featL;            // [16][32][32] = 16384 floats (exact fit)
    float* h0L  = featL;            // [32][68] = 2176 floats (after pacc dead)
    float* h1L  = featL + 2176;     // [32][36] = 1152 floats (disjoint)

    const int t     = threadIdx.x;
    const int chunk = blockIdx.x;
    const int b     = blockIdx.y;
    const int w0c   = chunk * CH_;

    // ======== async pw -> pwL (XOR swizzle applied on SOURCE address) ========
    // LDS linear granule g=(o<<7)|j holds pw granule (o, j^(o&7)); GEMM reads
    // pwL[o*512 + ((k4^(o&7))*4)] -> pw[o][k4]  (same involution both sides).
    {
        const int wid  = __builtin_amdgcn_readfirstlane(t >> 6);
        const int lane = t & 63;
        #pragma unroll
        for (int r = 0; r < 4; ++r) {
            const int g = wid * 256 + r * 64 + lane;
            const int o = g >> 7, j = g & 127;
            gload_lds16(pw + 4 * ((o << 7) + (j ^ (o & 7))), pwL + 4 * g);
        }
    }

    // ---- small weights: load + write LDS immediately (short live range) ----
    if (t < 512) {
        const float4 w0r = ((const float4*)w0g)[t];
        const float4 w1r = ((const float4*)w1g)[t];
        const int o0 = t >> 3, k40 = t & 7;        // w0: 64 rows x 8 f4
        *(float4*)&w0L[o0 * 36 + k40 * 4] = w0r;
        const int o1 = t >> 4, k41 = t & 15;       // w1: 32 rows x 16 f4
        *(float4*)&w1L[o1 * 68 + k41 * 4] = w1r;
    }
    if (t < 257) {
        float smv;
        if      (t <  32) smv = pb[t];
        else if (t <  96) smv = b0g[t - 32];
        else if (t < 160) smv = a0g[t - 96];
        else if (t < 192) smv = b1g[t - 160];
        else if (t < 224) smv = a1g[t - 192];
        else if (t < 256) smv = wog[t - 224];
        else              smv = bog[0];
        smalls[t] = smv;
    }

    // ---- stage twiddles + x tile ----
    if (t < 64) {
        float s, c;
        sincosf(6.28318530717958647692f * (float)t / 64.0f, &s, &c);
        twc[t] = c; tws[t] = s;
    }
    if (t < C_ * 96) {
        const int c = t / 96;
        const int j = t - c * 96;
        int gi = w0c + j; if (gi > T_ - 1) gi = T_ - 1;
        xtile[c][j] = x[((size_t)b * C_ + c) * T_ + gi];
    }
    __syncthreads();

    // ---- phase A: sliding DFT. thread = (quarter hh, channel cc, freq ff) ----
    {
        const int ff = t & 31;         // frequency 0..31
        const int cc = (t >> 5) & 7;   // channel 0..7
        const int hh = t >> 8;         // quarter 0..3 (8 w each)
        const float* xt = &xtile[cc][hh * 8];
        const float4* xt4 = (const float4*)xt;

        // seed: 64-tap DFT via 4 interleaved register-rotation chains
        const int f1 = ff, f2 = (2 * ff) & 63, f3 = (3 * ff) & 63, f4 = (4 * ff) & 63;
        float w0a = 1.f,      w0i = 0.f;
        float w1a = twc[f1],  w1i = -tws[f1];
        float w2a = twc[f2],  w2i = -tws[f2];
        float w3a = twc[f3],  w3i = -tws[f3];
        const float s4r = twc[f4], s4i = -tws[f4];
        float re = 0.f, im = 0.f;
        #pragma unroll 4
        for (int k4i = 0; k4i < 16; ++k4i) {
            const float4 xv = xt4[k4i];
            re = fmaf(xv.x, w0a, re); im = fmaf(xv.x, w0i, im);
            re = fmaf(xv.y, w1a, re); im = fmaf(xv.y, w1i, im);
            re = fmaf(xv.z, w2a, re); im = fmaf(xv.z, w2i, im);
            re = fmaf(xv.w, w3a, re); im = fmaf(xv.w, w3i, im);
            float tr;
            tr = w0a * s4r - w0i * s4i; w0i = w0a * s4i + w0i * s4r; w0a = tr;
            tr = w1a * s4r - w1i * s4i; w1i = w1a * s4i + w1i * s4r; w1a = tr;
            tr = w2a * s4r - w2i * s4i; w2i = w2a * s4i + w2i * s4r; w2a = tr;
            tr = w3a * s4r - w3i * s4i; w3i = w3a * s4i + w3i * s4r; w3a = tr;
        }

        // slide 8 windows, emitting (mag, ph); featL write k4-XOR-swizzled
        const float cf = twc[ff], sf = tws[ff];
        const int k4 = cc * 16 + (ff >> 1);
        const int sub = 2 * (ff & 1);
        #pragma unroll
        for (int g = 0; g < 2; ++g) {
            const float4 lo = *(const float4*)&xt[g * 4];
            const float4 hi = *(const float4*)&xt[g * 4 + 64];
            const float dl[4] = { hi.x - lo.x, hi.y - lo.y, hi.z - lo.z, hi.w - lo.w };
            #pragma unroll
            for (int j = 0; j < 4; ++j) {
                const float mag = __logf(1.0f + __builtin_amdgcn_sqrtf(re * re + im * im));
                const float ph  = fast_atan2pi(im, re);
                const int wrow = hh * 8 + g * 4 + j;
                const int k4s = k4 ^ (wrow & 7);
                *(float2*)&featL[wrow * 512 + k4s * 4 + sub] = make_float2(mag, ph);
                const float tt = re + dl[j];
                re = tt * cf - im * sf;
                im = tt * sf + im * cf;
            }
        }
    }
    __syncthreads();   // featL done + pwL async loads drained (vmcnt(0) at barrier)

    // ---- phase B: proj GEMM 32w x 32o, K=512, all-LDS, acc[4][4] ----
    // thread = ks(16) x wg(8) x og(8); w = wg+8i, o = og+8j
    {
        const int og = t & 7;
        const int wg = (t >> 3) & 7;
        const int ks = t >> 6;            // 0..15
        float acc[4][4];
        #pragma unroll
        for (int i = 0; i < 4; ++i)
            #pragma unroll
            for (int j = 0; j < 4; ++j) acc[i][j] = 0.f;

        #pragma unroll
        for (int jg = 0; jg < 8; ++jg) {
            const int k4 = ks * 8 + jg;
            float4 f[4], p[4];
            #pragma unroll
            for (int i = 0; i < 4; ++i)
                f[i] = *(const float4*)&featL[(wg + 8 * i) * 512 + ((k4 ^ wg) * 4)];
            #pragma unroll
            for (int j = 0; j < 4; ++j)
                p[j] = *(const float4*)&pwL[(og + 8 * j) * 512 + ((k4 ^ og) * 4)];
            #pragma unroll
            for (int i = 0; i < 4; ++i)
                #pragma unroll
                for (int j = 0; j < 4; ++j)
                    acc[i][j] = dot4(f[i], p[j], acc[i][j]);
        }
        __syncthreads();   // featL reads done; overlay with pacc
        #pragma unroll
        for (int i = 0; i < 4; ++i) {
            #pragma unroll
            for (int j = 0; j < 4; ++j) {
                const int w = wg + 8 * i, o = og + 8 * j;
                pacc[ks * 1024 + w * 32 + (o ^ ((w & 7) << 2))] = acc[i][j];
            }
        }
    }
    __syncthreads();

    // ---- finalize proj: reduce 16 K-slices, bias, tanh. 1 (w,o)/thread ----
    {
        const int o = t & 31;
        const int w = t >> 5;
        const int oS = o ^ ((w & 7) << 2);
        float s = smalls[o];               // pb
        #pragma unroll
        for (int q = 0; q < 16; ++q) s += pacc[q * 1024 + w * 32 + oS];
        projL[w * 36 + o] = fast_tanh(s) * PI_F;
    }
    __syncthreads();

    // ---- h0 = snake(proj @ w0^T + b0): thread = (w, outputs o and o+32) ----
    {
        const int w = t >> 5;          // 0..31 (broadcast within lane group)
        const int o = t & 31;
        float4 pr[8];
        #pragma unroll
        for (int q = 0; q < 8; ++q) pr[q] = *(const float4*)&projL[w * 36 + q * 4];
        #pragma unroll
        for (int k = 0; k < 2; ++k) {
            const int oo = o + 32 * k;
            float acc = 0.f;
            #pragma unroll
            for (int q = 0; q < 8; ++q)
                acc = dot4(pr[q], *(const float4*)&w0L[oo * 36 + q * 4], acc);
            const float hv = acc + smalls[32 + oo];
            const float aa = fabsf(smalls[96 + oo]) + 1e-8f;
            h0L[w * 68 + oo] = fast_snake(hv, fast_rcp(aa), aa);
        }
    }
    __syncthreads();

    // ---- h1 = snake(h0 @ w1^T + b1): thread = (w, 1 output), all-LDS ----
    {
        const int w = t >> 5;
        const int o = t & 31;
        float acc = 0.f;
        #pragma unroll 4
        for (int q = 0; q < 16; ++q)
            acc = dot4(*(const float4*)&h0L[w * 68 + q * 4],
                       *(const float4*)&w1L[o * 68 + q * 4], acc);
        const float hv = acc + smalls[160 + o];
        const float aa = fabsf(smalls[192 + o]) + 1e-8f;
        h1L[w * 36 + o] = fast_snake(hv, fast_rcp(aa), aa);
    }
    __syncthreads();

    // ---- out_t + softmax weight ----
    if (t < CH_) {
        const int w = t;
        float acc = 0.f;
        #pragma unroll
        for (int q = 0; q < 8; ++q)
            acc = dot4(*(const float4*)&h1L[w * 36 + q * 4],
                       *(const float4*)&smalls[224 + q * 4], acc);
        const float val = acc + smalls[256];
        const int wg = w0c + w;
        const float sw = (wg < W_) ? __expf(agg[wg] - stats[0]) / stats[1] : 0.f;
        chunkAcc[w] = val * sw;
    }
    __syncthreads();

    // ---- reduce 32 chunk values -> 1 partial ----
    if (t < 32) {
        float vs = chunkAcc[t];
        vs += __shfl_down(vs, 16);
        vs += __shfl_down(vs, 8);
        vs += __shfl_down(vs, 4);
        vs += __shfl_down(vs, 2);
        vs += __shfl_down(vs, 1);
        if (t == 0) partial[(size_t)chunk * B_ + b] = vs;
    }
}

// ---------------------------------------------------------------------------
// K3: final reduce over chunks -> d_out[b]
// ---------------------------------------------------------------------------
__global__ void k_reduce(const float* __restrict__ partial, float* __restrict__ out)
{
    const int b = threadIdx.x;
    if (b < B_) {
        float s = 0.f;
        for (int c = 0; c < NCHUNK_; ++c) s += partial[(size_t)c * B_ + b];
        out[b] = s;
    }
}

// ---------------------------------------------------------------------------
extern "C" void kernel_launch(void* const* d_in, const int* in_sizes, int n_in,
                              void* d_out, int out_size, void* d_ws, size_t ws_size,
                              hipStream_t stream)
{
    const float* x   = (const float*)d_in[0];
    const float* pw  = (const float*)d_in[1];
    const float* pb  = (const float*)d_in[2];
    const float* w0  = (const float*)d_in[3];
    const float* b0  = (const float*)d_in[4];
    const float* a0  = (const float*)d_in[5];
    const float* w1  = (const float*)d_in[6];
    const float* b1  = (const float*)d_in[7];
    const float* a1  = (const float*)d_in[8];
    const float* wo  = (const float*)d_in[9];
    const float* bo  = (const float*)d_in[10];
    const float* agg = (const float*)d_in[11];
    float* ws  = (float*)d_ws;
    float* out = (float*)d_out;

    k_softmax_stats<<<1, 256, 0, stream>>>(agg, ws);
    dim3 grid(NCHUNK_, B_);
    k_main<<<grid, 1024, 0, stream>>>(x, pw, pb, w0, b0, a0, w1, b1, a1, wo, bo,
                                      agg, ws, ws + 2);
    k_reduce<<<1, 64, 0, stream>>>(ws + 2, out);
}

// Round 7
// 170.320 us; speedup vs baseline: 7.7854x; 1.3110x over previous
//
#include <hip/hip_runtime.h>
#include <math.h>

#define B_ 64
#define C_ 8
#define T_ 2048
#define K_ 64
#define NF_ 32
#define FFT_DIM_ 512
#define MLP_ 32
#define HID_ 64
#define W_ 1985
#define CH_ 32
#define NCHUNK_ 63   /* ceil(1985/32) */
#define PI_F 3.14159265358979323846f

typedef _Float16 f16x8 __attribute__((ext_vector_type(8)));
typedef _Float16 f16x2 __attribute__((ext_vector_type(2)));
typedef float    f32x4 __attribute__((ext_vector_type(4)));

// ---------------- fast inline transcendentals (branchless) ----------------
__device__ __forceinline__ float fast_rcp(float x) { return __builtin_amdgcn_rcpf(x); }

// atan2(y,x)/pi, max err ~1e-6.
__device__ __forceinline__ float fast_atan2pi(float y, float x)
{
    const float ax = fabsf(x), ay = fabsf(y);
    const float mx = fmaxf(ax, ay), mn = fminf(ax, ay);
    const float r  = mn * fast_rcp(fmaxf(mx, 1e-30f));
    const float t  = r * r;
    float a = -0.003730950f;
    a = fmaf(a, t,  0.016759940f);
    a = fmaf(a, t, -0.037059946f);
    a = fmaf(a, t,  0.061602941f);
    a = fmaf(a, t, -0.105877528f);
    a = fmaf(a, t,  0.318302656f);
    a *= r;
    a = (ay > ax) ? (0.5f - a) : a;
    a = (x < 0.0f) ? (1.0f - a) : a;
    return copysignf(a, y);
}

__device__ __forceinline__ float fast_tanh(float x)
{
    const float e = __expf(2.0f * x);
    return 1.0f - 2.0f * fast_rcp(e + 1.0f);
}

__device__ __forceinline__ float fast_snake(float h, float rcp_aa, float aa)
{
    const float s = __sinf(aa * h);
    return h + s * s * rcp_aa;
}

__device__ __forceinline__ float dot4(float4 a, float4 b, float acc)
{
    return fmaf(a.x, b.x, fmaf(a.y, b.y, fmaf(a.z, b.z, fmaf(a.w, b.w, acc))));
}

// ---------------------------------------------------------------------------
// K1: softmax stats over agg (W,) -> ws[0]=max, ws[1]=sum(exp(agg-max))
// ---------------------------------------------------------------------------
__global__ __launch_bounds__(256) void k_softmax_stats(
    const float* __restrict__ agg, float* __restrict__ ws)
{
    __shared__ float red[256];
    const int t = threadIdx.x;
    float m = -1e30f;
    for (int i = t; i < W_; i += 256) m = fmaxf(m, agg[i]);
    red[t] = m;
    __syncthreads();
    for (int s = 128; s > 0; s >>= 1) {
        if (t < s) red[t] = fmaxf(red[t], red[t + s]);
        __syncthreads();
    }
    const float mx = red[0];
    __syncthreads();
    float sum = 0.f;
    for (int i = t; i < W_; i += 256) sum += __expf(agg[i] - mx);
    red[t] = sum;
    __syncthreads();
    for (int s = 128; s > 0; s >>= 1) {
        if (t < s) red[t] += red[t + s];
        __syncthreads();
    }
    if (t == 0) { ws[0] = mx; ws[1] = red[0]; }
}

// ---------------------------------------------------------------------------
// K2: sliding-DFT (waves 0-7, 16 slides/chain) || pw->fp16 convert (waves 8-15)
//     then 3-pass fp16 MFMA proj GEMM + scalar MLP. 1024 thr, ~155 KB LDS.
// ---------------------------------------------------------------------------
__global__ __launch_bounds__(1024) void k_main(
    const float* __restrict__ x,  const float* __restrict__ pw,
    const float* __restrict__ pb, const float* __restrict__ w0g,
    const float* __restrict__ b0g,const float* __restrict__ a0g,
    const float* __restrict__ w1g,const float* __restrict__ b1g,
    const float* __restrict__ a1g,const float* __restrict__ wog,
    const float* __restrict__ bog,const float* __restrict__ agg,
    const float* __restrict__ stats, float* __restrict__ partial)
{
    // A (features) and B (pw) as fp16 hi/lo, [32][512], 16B-granule XOR swizzle
    __shared__ __align__(16) _Float16 AhiL[32 * 512];   // 32768 B
    __shared__ __align__(16) _Float16 AloL[32 * 512];   // 32768 B
    __shared__ __align__(16) _Float16 BhiL[32 * 512];   // 32768 B
    __shared__ __align__(16) _Float16 BloL[32 * 512];   // 32768 B
    __shared__ __align__(16) float w0L[64 * 36];        // 9216 B
    __shared__ __align__(16) float w1L[32 * 68];        // 8704 B
    __shared__ __align__(16) float projL[32 * 36];      // 4608 B
    __shared__ __align__(16) float xtile[C_][100];      // 3200 B
    __shared__ float twc[64], tws[64];
    __shared__ float smalls[260];   // [0..31]=pb [32..95]=b0 [96..159]=a0
                                    // [160..191]=b1 [192..223]=a1 [224..255]=wo [256]=bo
    __shared__ float chunkAcc[CH_];

    // overlays inside AhiL/AloL (dead after GEMM; barriers between uses):
    float* pacc = (float*)AhiL;            // [4][32][33] = 4224 floats (16896 B)
    float* h0L  = (float*)AhiL;            // [32][68] = 2176 floats (after pacc dead)
    float* h1L  = (float*)AhiL + 2176;     // [32][36] = 1152 floats (disjoint)

    const int t     = threadIdx.x;
    const int chunk = blockIdx.x;
    const int b     = blockIdx.y;
    const int w0c   = chunk * CH_;

    // ---- stage: twiddles, x tile, smalls, w0L, w1L ----
    if (t < 64) {
        float s, c;
        sincosf(6.28318530717958647692f * (float)t / 64.0f, &s, &c);
        twc[t] = c; tws[t] = s;
    }
    if (t < C_ * 96) {
        const int c = t / 96;
        const int j = t - c * 96;
        int gi = w0c + j; if (gi > T_ - 1) gi = T_ - 1;
        xtile[c][j] = x[((size_t)b * C_ + c) * T_ + gi];
    }
    if (t < 257) {
        float smv;
        if      (t <  32) smv = pb[t];
        else if (t <  96) smv = b0g[t - 32];
        else if (t < 160) smv = a0g[t - 96];
        else if (t < 192) smv = b1g[t - 160];
        else if (t < 224) smv = a1g[t - 192];
        else if (t < 256) smv = wog[t - 224];
        else              smv = bog[0];
        smalls[t] = smv;
    }
    if (t < 512) {
        const float4 w0r = ((const float4*)w0g)[t];
        const int o0 = t >> 3, k40 = t & 7;        // w0: 64 rows x 8 f4
        *(float4*)&w0L[o0 * 36 + k40 * 4] = w0r;
    } else {
        const int u = t - 512;
        const float4 w1r = ((const float4*)w1g)[u];
        const int o1 = u >> 4, k41 = u & 15;       // w1: 32 rows x 16 f4
        *(float4*)&w1L[o1 * 68 + k41 * 4] = w1r;
    }
    __syncthreads();

    // ---- phase A (waves 0-7): sliding DFT, 16 slides/chain ||
    //      (waves 8-15): pw fp32 -> Bhi/Blo fp16 in LDS ----
    if (t < 512) {
        const int ff = t & 31;         // frequency 0..31
        const int cc = (t >> 5) & 7;   // channel 0..7
        const int hh = t >> 8;         // half 0..1 (16 w each)
        const float* xt = &xtile[cc][hh * 16];
        const float4* xt4 = (const float4*)xt;

        // seed: 64-tap DFT via 4 interleaved register-rotation chains
        const int f1 = ff, f2 = (2 * ff) & 63, f3 = (3 * ff) & 63, f4 = (4 * ff) & 63;
        float w0a = 1.f,      w0i = 0.f;
        float w1a = twc[f1],  w1i = -tws[f1];
        float w2a = twc[f2],  w2i = -tws[f2];
        float w3a = twc[f3],  w3i = -tws[f3];
        const float s4r = twc[f4], s4i = -tws[f4];
        float re = 0.f, im = 0.f;
        #pragma unroll 4
        for (int k4i = 0; k4i < 16; ++k4i) {
            const float4 xv = xt4[k4i];
            re = fmaf(xv.x, w0a, re); im = fmaf(xv.x, w0i, im);
            re = fmaf(xv.y, w1a, re); im = fmaf(xv.y, w1i, im);
            re = fmaf(xv.z, w2a, re); im = fmaf(xv.z, w2i, im);
            re = fmaf(xv.w, w3a, re); im = fmaf(xv.w, w3i, im);
            float tr;
            tr = w0a * s4r - w0i * s4i; w0i = w0a * s4i + w0i * s4r; w0a = tr;
            tr = w1a * s4r - w1i * s4i; w1i = w1a * s4i + w1i * s4r; w1a = tr;
            tr = w2a * s4r - w2i * s4i; w2i = w2a * s4i + w2i * s4r; w2a = tr;
            tr = w3a * s4r - w3i * s4i; w3i = w3a * s4i + w3i * s4r; w3a = tr;
        }

        // slide 16 windows; emit (mag,ph) as fp16 hi/lo, XOR-swizzled granules
        const float cf = twc[ff], sf = tws[ff];
        const int gA   = cc * 8 + (ff >> 2);     // 16B granule (8 halves)
        const int subA = 2 * (ff & 3);           // half offset within granule
        #pragma unroll
        for (int g = 0; g < 4; ++g) {
            const float4 lo4 = *(const float4*)&xt[g * 4];
            const float4 hi4 = *(const float4*)&xt[g * 4 + 64];
            const float dl[4] = { hi4.x - lo4.x, hi4.y - lo4.y,
                                  hi4.z - lo4.z, hi4.w - lo4.w };
            #pragma unroll
            for (int j = 0; j < 4; ++j) {
                const float mag = __logf(1.0f + __builtin_amdgcn_sqrtf(re * re + im * im));
                const float ph  = fast_atan2pi(im, re);
                const int wrow = hh * 16 + g * 4 + j;
                const int gs = gA ^ (wrow & 7);
                const _Float16 mh = (_Float16)mag;
                const _Float16 qh = (_Float16)ph;
                f16x2 vh; vh[0] = mh; vh[1] = qh;
                f16x2 vl;
                vl[0] = (_Float16)(mag - (float)mh);
                vl[1] = (_Float16)(ph  - (float)qh);
                *(f16x2*)&AhiL[wrow * 512 + gs * 8 + subA] = vh;
                *(f16x2*)&AloL[wrow * 512 + gs * 8 + subA] = vl;
                const float tt = re + dl[j];
                re = tt * cf - im * sf;
                im = tt * sf + im * cf;
            }
        }
    } else {
        // pw conversion: thread u -> row o = u>>4, k block (u&15)*32 (32 elems)
        const int u  = t - 512;
        const int o  = u >> 4;
        const int kb = (u & 15) * 32;
        const float4* pw4 = (const float4*)(pw + (size_t)o * 512 + kb);
        #pragma unroll
        for (int gb = 0; gb < 4; ++gb) {
            const float4 va = pw4[2 * gb];
            const float4 vb = pw4[2 * gb + 1];
            const float vv[8] = { va.x, va.y, va.z, va.w, vb.x, vb.y, vb.z, vb.w };
            f16x8 hi, lo;
            #pragma unroll
            for (int e = 0; e < 8; ++e) {
                const _Float16 h = (_Float16)vv[e];
                hi[e] = h;
                lo[e] = (_Float16)(vv[e] - (float)h);
            }
            const int gg = (((u & 15) * 4 + gb) ^ (o & 7));
            *(f16x8*)&BhiL[o * 512 + gg * 8] = hi;
            *(f16x8*)&BloL[o * 512 + gg * 8] = lo;
        }
    }
    __syncthreads();

    // ---- phase B: proj GEMM via fp16 MFMA, 3-pass split precision ----
    // wave = (C-tile wt,ot) x K-quarter kq; 12 MFMA/wave; fp32 accumulate
    {
        const int wid  = t >> 6;
        const int lane = t & 63;
        const int wt = (wid >> 1) & 1;    // w 16-block
        const int ot = wid & 1;           // o 16-block
        const int kq = wid >> 2;          // K quarter (128 k)
        const int m16 = lane & 15;        // A-row / B-col / C-col
        const int kl  = lane >> 4;        // k-subgroup
        const int arow = wt * 16 + m16;
        const int brow = ot * 16 + m16;
        f32x4 acc = {0.f, 0.f, 0.f, 0.f};
        #pragma unroll
        for (int j = 0; j < 4; ++j) {
            const int ks = kq * 4 + j;
            const int ga = ((ks * 4 + kl) ^ (arow & 7)) * 8;
            const int gb = ((ks * 4 + kl) ^ (brow & 7)) * 8;
            const f16x8 ah = *(const f16x8*)&AhiL[arow * 512 + ga];
            const f16x8 al = *(const f16x8*)&AloL[arow * 512 + ga];
            const f16x8 bh = *(const f16x8*)&BhiL[brow * 512 + gb];
            const f16x8 bl = *(const f16x8*)&BloL[brow * 512 + gb];
            acc = __builtin_amdgcn_mfma_f32_16x16x32_f16(ah, bh, acc, 0, 0, 0);
            acc = __builtin_amdgcn_mfma_f32_16x16x32_f16(al, bh, acc, 0, 0, 0);
            acc = __builtin_amdgcn_mfma_f32_16x16x32_f16(ah, bl, acc, 0, 0, 0);
        }
        __syncthreads();   // all A/B LDS reads done before pacc overlays AhiL
        #pragma unroll
        for (int r = 0; r < 4; ++r) {
            const int w = wt * 16 + kl * 4 + r;   // C row
            const int o = ot * 16 + m16;          // C col
            pacc[kq * 1056 + w * 33 + o] = acc[r];
        }
    }
    __syncthreads();

    // ---- finalize proj: reduce 4 K-quarters, bias, tanh. 1 (w,o)/thread ----
    {
        const int o = t & 31;
        const int w = t >> 5;
        float s = smalls[o];               // pb
        #pragma unroll
        for (int q = 0; q < 4; ++q) s += pacc[q * 1056 + w * 33 + o];
        projL[w * 36 + o] = fast_tanh(s) * PI_F;
    }
    __syncthreads();   // pacc dead; h0L overlay safe

    // ---- h0 = snake(proj @ w0^T + b0): thread = (w, outputs o and o+32) ----
    {
        const int w = t >> 5;
        const int o = t & 31;
        float4 pr[8];
        #pragma unroll
        for (int q = 0; q < 8; ++q) pr[q] = *(const float4*)&projL[w * 36 + q * 4];
        #pragma unroll
        for (int k = 0; k < 2; ++k) {
            const int oo = o + 32 * k;
            float acc = 0.f;
            #pragma unroll
            for (int q = 0; q < 8; ++q)
                acc = dot4(pr[q], *(const float4*)&w0L[oo * 36 + q * 4], acc);
            const float hv = acc + smalls[32 + oo];
            const float aa = fabsf(smalls[96 + oo]) + 1e-8f;
            h0L[w * 68 + oo] = fast_snake(hv, fast_rcp(aa), aa);
        }
    }
    __syncthreads();

    // ---- h1 = snake(h0 @ w1^T + b1): thread = (w, 1 output) ----
    {
        const int w = t >> 5;
        const int o = t & 31;
        float acc = 0.f;
        #pragma unroll 4
        for (int q = 0; q < 16; ++q)
            acc = dot4(*(const float4*)&h0L[w * 68 + q * 4],
                       *(const float4*)&w1L[o * 68 + q * 4], acc);
        const float hv = acc + smalls[160 + o];
        const float aa = fabsf(smalls[192 + o]) + 1e-8f;
        h1L[w * 36 + o] = fast_snake(hv, fast_rcp(aa), aa);
    }
    __syncthreads();

    // ---- out_t + softmax weight ----
    if (t < CH_) {
        const int w = t;
        float acc = 0.f;
        #pragma unroll
        for (int q = 0; q < 8; ++q)
            acc = dot4(*(const float4*)&h1L[w * 36 + q * 4],
                       *(const float4*)&smalls[224 + q * 4], acc);
        const float val = acc + smalls[256];
        const int wg = w0c + w;
        const float sw = (wg < W_) ? __expf(agg[wg] - stats[0]) / stats[1] : 0.f;
        chunkAcc[w] = val * sw;
    }
    __syncthreads();

    // ---- reduce 32 chunk values -> 1 partial ----
    if (t < 32) {
        float vs = chunkAcc[t];
        vs += __shfl_down(vs, 16);
        vs += __shfl_down(vs, 8);
        vs += __shfl_down(vs, 4);
        vs += __shfl_down(vs, 2);
        vs += __shfl_down(vs, 1);
        if (t == 0) partial[(size_t)chunk * B_ + b] = vs;
    }
}

// ---------------------------------------------------------------------------
// K3: final reduce over chunks -> d_out[b]
// ---------------------------------------------------------------------------
__global__ void k_reduce(const float* __restrict__ partial, float* __restrict__ out)
{
    const int b = threadIdx.x;
    if (b < B_) {
        float s = 0.f;
        for (int c = 0; c < NCHUNK_; ++c) s += partial[(size_t)c * B_ + b];
        out[b] = s;
    }
}

// ---------------------------------------------------------------------------
extern "C" void kernel_launch(void* const* d_in, const int* in_sizes, int n_in,
                              void* d_out, int out_size, void* d_ws, size_t ws_size,
                              hipStream_t stream)
{
    const float* x   = (const float*)d_in[0];
    const float* pw  = (const float*)d_in[1];
    const float* pb  = (const float*)d_in[2];
    const float* w0  = (const float*)d_in[3];
    const float* b0  = (const float*)d_in[4];
    const float* a0  = (const float*)d_in[5];
    const float* w1  = (const float*)d_in[6];
    const float* b1  = (const float*)d_in[7];
    const float* a1  = (const float*)d_in[8];
    const float* wo  = (const float*)d_in[9];
    const float* bo  = (const float*)d_in[10];
    const float* agg = (const float*)d_in[11];
    float* ws  = (float*)d_ws;
    float* out = (float*)d_out;

    k_softmax_stats<<<1, 256, 0, stream>>>(agg, ws);
    dim3 grid(NCHUNK_, B_);
    k_main<<<grid, 1024, 0, stream>>>(x, pw, pb, w0, b0, a0, w1, b1, a1, wo, bo,
                                      agg, ws, ws + 2);
    k_reduce<<<1, 64, 0, stream>>>(ws + 2, out);
}